// Round 1
// baseline (963.954 us; speedup 1.0000x reference)
//
#include <hip/hip_runtime.h>
#include <math.h>

#define NN 2048

// ---------------------------------------------------------------------------
// Exclusive prefix-sum over node index, one wave per feature.
// agg[j][f] = sum_{i<j} X[i][f]   (the GIN aggregation for triu edges)
// ---------------------------------------------------------------------------
__global__ void k_cumsum(const float* __restrict__ X, float* __restrict__ AGG, int Fdim) {
  int lane = threadIdx.x & 63;
  int f = blockIdx.x * (blockDim.x >> 6) + (threadIdx.x >> 6);
  if (f >= Fdim) return;
  float v[32];
#pragma unroll
  for (int c = 0; c < 32; c++) v[c] = X[(size_t)(c * 64 + lane) * Fdim + f];
  float carry = 0.f;
#pragma unroll
  for (int c = 0; c < 32; c++) {
    float s = v[c];
#pragma unroll
    for (int d = 1; d < 64; d <<= 1) {
      float t = __shfl_up(s, d);
      s += (lane >= d) ? t : 0.f;
    }
    AGG[(size_t)(c * 64 + lane) * Fdim + f] = carry + (s - v[c]);
    carry += __shfl(s, 63);
  }
}

// Same, but first applies the mid-layer BatchNorm affine (computed from the
// accumulated double-precision stats) and also writes the normalized h2n.
__global__ void k_cumsum_bn(const float* __restrict__ X, float* __restrict__ Y,
                            float* __restrict__ AGG, const double* __restrict__ statsM,
                            const float* __restrict__ g, const float* __restrict__ bb) {
  int lane = threadIdx.x & 63;
  int f = blockIdx.x * (blockDim.x >> 6) + (threadIdx.x >> 6);
  if (f >= 64) return;
  double mean = statsM[f] * (1.0 / 2048.0);
  double var = statsM[64 + f] * (1.0 / 2048.0) - mean * mean;
  if (var < 0.0) var = 0.0;
  float a = (float)((double)g[f] / sqrt(var + 1e-5));
  float bsh = fmaf(-(float)mean, a, bb[f]);
  float v[32];
#pragma unroll
  for (int c = 0; c < 32; c++)
    v[c] = fmaf(a, X[(size_t)(c * 64 + lane) * 64 + f], bsh);
  float carry = 0.f;
#pragma unroll
  for (int c = 0; c < 32; c++) {
    float s = v[c];
#pragma unroll
    for (int d = 1; d < 64; d <<= 1) {
      float t = __shfl_up(s, d);
      s += (lane >= d) ? t : 0.f;
    }
    Y[(size_t)(c * 64 + lane) * 64 + f] = v[c];
    AGG[(size_t)(c * 64 + lane) * 64 + f] = carry + (s - v[c]);
    carry += __shfl(s, 63);
  }
}

// ---------------------------------------------------------------------------
// Fused GIN MLP: OUT = relu(relu(((1+eps)X + AGG) @ Wa + ba) @ Wb + bb)
// Optional: add xinit (layer 3), accumulate BN stats (layer 2).
// 64 nodes per block, 256 threads.
// ---------------------------------------------------------------------------
template <int FIN, int FOUT, bool STATS, bool ADDX>
__global__ __launch_bounds__(256) void k_mlp(
    const float* __restrict__ X, const float* __restrict__ AGG,
    const float* __restrict__ epsp,
    const float* __restrict__ Wa, const float* __restrict__ ba,
    const float* __restrict__ Wb, const float* __restrict__ bb,
    float* __restrict__ OUT, const float* __restrict__ XINIT,
    double* __restrict__ stats) {
  __shared__ float xh[64][FIN + 1];
  __shared__ float Was[FIN][64];
  __shared__ float Ts[64][65];
  __shared__ float Wbs[64][FOUT];
  __shared__ float bas[64];
  __shared__ float bbs[FOUT];
  __shared__ float ssum[64];
  __shared__ float ssq[64];
  int tid = threadIdx.x;
  int node0 = blockIdx.x * 64;
  float ep = 1.f + epsp[0];
  for (int idx = tid; idx < 64 * FIN; idx += 256) {
    int n = idx / FIN, f = idx - n * FIN;
    size_t gidx = (size_t)(node0 + n) * FIN + f;
    xh[n][f] = fmaf(ep, X[gidx], AGG[gidx]);
  }
  for (int idx = tid; idx < FIN * 64; idx += 256) Was[idx >> 6][idx & 63] = Wa[idx];
  for (int idx = tid; idx < 64 * FOUT; idx += 256) Wbs[idx / FOUT][idx % FOUT] = Wb[idx];
  if (tid < 64) bas[tid] = ba[tid];
  if (tid < FOUT) bbs[tid] = bb[tid];
  if (STATS && tid < 64) { ssum[tid] = 0.f; ssq[tid] = 0.f; }
  __syncthreads();
  // Phase A: T = relu(xh @ Wa + ba)  (Hmid = 64)
  {
    int n = tid >> 2, c0 = (tid & 3) * 16;
    float acc[16];
#pragma unroll
    for (int k = 0; k < 16; k++) acc[k] = bas[c0 + k];
    for (int f = 0; f < FIN; f++) {
      float xv = xh[n][f];
#pragma unroll
      for (int k = 0; k < 16; k++) acc[k] = fmaf(xv, Was[f][c0 + k], acc[k]);
    }
#pragma unroll
    for (int k = 0; k < 16; k++) Ts[n][c0 + k] = fmaxf(acc[k], 0.f);
  }
  __syncthreads();
  // Phase B: OUT = relu(T @ Wb + bb) (+xinit) (+stats)
  {
    constexpr int CC = FOUT / 4;
    int n = tid >> 2, c0 = (tid & 3) * CC;
    float acc[CC];
#pragma unroll
    for (int k = 0; k < CC; k++) acc[k] = bbs[c0 + k];
    for (int f = 0; f < 64; f++) {
      float tv = Ts[n][f];
#pragma unroll
      for (int k = 0; k < CC; k++) acc[k] = fmaf(tv, Wbs[f][c0 + k], acc[k]);
    }
#pragma unroll
    for (int k = 0; k < CC; k++) {
      float r = fmaxf(acc[k], 0.f);
      if (STATS) {
        atomicAdd(&ssum[c0 + k], r);
        atomicAdd(&ssq[c0 + k], r * r);
      }
      if (ADDX) r += XINIT[(size_t)(node0 + n) * FOUT + c0 + k];
      OUT[(size_t)(node0 + n) * FOUT + c0 + k] = r;
    }
  }
  if (STATS) {
    __syncthreads();
    if (tid < 64) {
      atomicAdd(&stats[tid], (double)ssum[tid]);
      atomicAdd(&stats[64 + tid], (double)ssq[tid]);
    }
  }
}

// ---------------------------------------------------------------------------
// Edge pass 1: accumulate per-channel sum / sumsq of e = leaky(z) over all
// valid pairs i<j.  16x16 pair tiles, upper triangle only.
// ---------------------------------------------------------------------------
__global__ __launch_bounds__(256) void k_edge1(
    const float* __restrict__ H3, const float* __restrict__ W5,
    const float* __restrict__ b5, double* __restrict__ stats5) {
  int bi = blockIdx.y, bj = blockIdx.x;
  if (bi > bj) return;
  __shared__ float hI[16][33], hJ[16][33];
  __shared__ float W5s[2048];
  __shared__ float b5s[64];
  __shared__ float ssum[64], ssq[64];
  int tid = threadIdx.x;
  for (int idx = tid; idx < 512; idx += 256) {
    int n = idx >> 5, f = idx & 31;
    hI[n][f] = H3[(size_t)(bi * 16 + n) * 32 + f];
    hJ[n][f] = H3[(size_t)(bj * 16 + n) * 32 + f];
  }
  for (int idx = tid; idx < 2048; idx += 256) W5s[idx] = W5[idx];
  if (tid < 64) { b5s[tid] = b5[tid]; ssum[tid] = 0.f; ssq[tid] = 0.f; }
  __syncthreads();
  int ty = tid >> 4, tx = tid & 15;
  int i = bi * 16 + ty, j = bj * 16 + tx;
  bool valid = i < j;
  float m[32];
#pragma unroll
  for (int f = 0; f < 32; f++) m[f] = hI[ty][f] * hJ[tx][f];
  for (int cc = 0; cc < 4; cc++) {
    int c0 = cc * 16;
    float z[16];
#pragma unroll
    for (int k = 0; k < 16; k++) z[k] = b5s[c0 + k];
#pragma unroll
    for (int f = 0; f < 32; f++) {
      float mf = m[f];
#pragma unroll
      for (int k = 0; k < 16; k++) z[k] = fmaf(mf, W5s[f * 64 + c0 + k], z[k]);
    }
    float sq[16];
#pragma unroll
    for (int k = 0; k < 16; k++) {
      float e = z[k] > 0.f ? z[k] : 0.01f * z[k];
      e = valid ? e : 0.f;
      z[k] = e;
      sq[k] = e * e;
    }
    // reduce across the 16 tx lanes of each quarter-wave (xor bits 0..3)
#pragma unroll
    for (int d = 1; d < 16; d <<= 1) {
#pragma unroll
      for (int k = 0; k < 16; k++) {
        z[k] += __shfl_xor(z[k], d);
        sq[k] += __shfl_xor(sq[k], d);
      }
    }
    if (tx == 0) {
#pragma unroll
      for (int k = 0; k < 16; k++) {
        atomicAdd(&ssum[c0 + k], z[k]);
        atomicAdd(&ssq[c0 + k], sq[k]);
      }
    }
  }
  __syncthreads();
  int rep = (blockIdx.y * gridDim.x + blockIdx.x) & 63;  // 64-way replicated stats
  if (tid < 64) {
    atomicAdd(&stats5[rep * 128 + tid], (double)ssum[tid]);
    atomicAdd(&stats5[rep * 128 + 64 + tid], (double)ssq[tid]);
  }
}

// Fold replicated stats into BN scale/shift.
__global__ void k_prep5(const double* __restrict__ stats5, const float* __restrict__ g,
                        const float* __restrict__ bb, float* __restrict__ prep, double ecnt) {
  int c = threadIdx.x;
  if (c >= 64) return;
  double s1 = 0.0, s2 = 0.0;
  for (int r = 0; r < 64; r++) {
    s1 += stats5[r * 128 + c];
    s2 += stats5[r * 128 + 64 + c];
  }
  double mean = s1 / ecnt;
  double var = s2 / ecnt - mean * mean;
  if (var < 0.0) var = 0.0;
  float a = (float)((double)g[c] / sqrt(var + 1e-5));
  prep[c] = a;
  prep[64 + c] = (float)((double)bb[c] - mean * (double)a);
}

// ---------------------------------------------------------------------------
// Edge pass 2: recompute z, apply BN + W6 + softmax, scatter symmetric probs.
// ---------------------------------------------------------------------------
__global__ __launch_bounds__(256) void k_edge2(
    const float* __restrict__ H3, const float* __restrict__ W5,
    const float* __restrict__ b5, const float* __restrict__ prep,
    const float* __restrict__ W6, const float* __restrict__ b6,
    float* __restrict__ out) {
  int bi = blockIdx.y, bj = blockIdx.x;
  if (bi > bj) return;
  __shared__ float hI[16][33], hJ[16][33];
  __shared__ float W5s[2048];
  __shared__ float b5s[64], scs[64], shs[64], w6a[64], w6b[64];
  int tid = threadIdx.x;
  for (int idx = tid; idx < 512; idx += 256) {
    int n = idx >> 5, f = idx & 31;
    hI[n][f] = H3[(size_t)(bi * 16 + n) * 32 + f];
    hJ[n][f] = H3[(size_t)(bj * 16 + n) * 32 + f];
  }
  for (int idx = tid; idx < 2048; idx += 256) W5s[idx] = W5[idx];
  if (tid < 64) {
    b5s[tid] = b5[tid];
    scs[tid] = prep[tid];
    shs[tid] = prep[64 + tid];
    w6a[tid] = W6[tid * 2];
    w6b[tid] = W6[tid * 2 + 1];
  }
  __syncthreads();
  int ty = tid >> 4, tx = tid & 15;
  int i = bi * 16 + ty, j = bj * 16 + tx;
  float m[32];
#pragma unroll
  for (int f = 0; f < 32; f++) m[f] = hI[ty][f] * hJ[tx][f];
  float l0 = b6[0], l1 = b6[1];
  for (int cc = 0; cc < 4; cc++) {
    int c0 = cc * 16;
    float z[16];
#pragma unroll
    for (int k = 0; k < 16; k++) z[k] = b5s[c0 + k];
#pragma unroll
    for (int f = 0; f < 32; f++) {
      float mf = m[f];
#pragma unroll
      for (int k = 0; k < 16; k++) z[k] = fmaf(mf, W5s[f * 64 + c0 + k], z[k]);
    }
#pragma unroll
    for (int k = 0; k < 16; k++) {
      int c = c0 + k;
      float e = z[k] > 0.f ? z[k] : 0.01f * z[k];
      float en = fmaf(e, scs[c], shs[c]);
      l0 = fmaf(en, w6a[c], l0);
      l1 = fmaf(en, w6b[c], l1);
    }
  }
  float mx = fmaxf(l0, l1);
  float e0 = expf(l0 - mx), e1 = expf(l1 - mx);
  float inv = 1.f / (e0 + e1);
  float2 p;
  p.x = e0 * inv;
  p.y = e1 * inv;
  if (i < j) {
    *(float2*)(out + ((size_t)i * NN + j) * 2) = p;
    *(float2*)(out + ((size_t)j * NN + i) * 2) = p;
  } else if (i == j) {
    float2 zz;
    zz.x = 0.f;
    zz.y = 0.f;
    *(float2*)(out + ((size_t)i * NN + i) * 2) = zz;  // diagonal must be zeroed (d_out poisoned)
  }
}

// ---------------------------------------------------------------------------
extern "C" void kernel_launch(void* const* d_in, const int* in_sizes, int n_in,
                              void* d_out, int out_size, void* d_ws, size_t ws_size,
                              hipStream_t stream) {
  const float* nf   = (const float*)d_in[1];
  const float* eps1 = (const float*)d_in[2];
  const float* W1a  = (const float*)d_in[3];
  const float* b1a  = (const float*)d_in[4];
  const float* W1b  = (const float*)d_in[5];
  const float* b1b  = (const float*)d_in[6];
  const float* epsm = (const float*)d_in[7];
  const float* Wma  = (const float*)d_in[8];
  const float* bma  = (const float*)d_in[9];
  const float* Wmb  = (const float*)d_in[10];
  const float* bmb  = (const float*)d_in[11];
  const float* bnmg = (const float*)d_in[12];
  const float* bnmb = (const float*)d_in[13];
  const float* epsl = (const float*)d_in[14];
  const float* Wla  = (const float*)d_in[15];
  const float* bla  = (const float*)d_in[16];
  const float* Wlb  = (const float*)d_in[17];
  const float* blb  = (const float*)d_in[18];
  const float* W5   = (const float*)d_in[19];
  const float* b5   = (const float*)d_in[20];
  const float* bn5g = (const float*)d_in[21];
  const float* bn5b = (const float*)d_in[22];
  const float* W6   = (const float*)d_in[23];
  const float* b6   = (const float*)d_in[24];
  double ecnt = (double)in_sizes[25];
  float* out = (float*)d_out;

  // workspace layout (floats); doubles 8B-aligned at the tail
  float* w = (float*)d_ws;
  float* agg  = w;               // 2048*64
  float* h1   = w + 131072;      // 2048*64
  float* h2   = w + 262144;      // 2048*64
  float* h2n  = w + 393216;      // 2048*64
  float* h3   = w + 524288;      // 2048*32
  float* prep = w + 589824;      // 128
  double* statsM = (double*)(w + 589952);  // 128 doubles
  double* stats5 = (double*)(w + 590208);  // 64*128 doubles

  hipMemsetAsync((void*)statsM, 0, 1024 + 65536, stream);

  // conv1: agg = cumsum(nf); h1 = mlp
  k_cumsum<<<8, 256, 0, stream>>>(nf, agg, 32);
  k_mlp<32, 64, false, false><<<32, 256, 0, stream>>>(nf, agg, eps1, W1a, b1a, W1b, b1b, h1, nullptr, nullptr);
  // conv mid: agg = cumsum(h1); h2 = mlp (+BN stats)
  k_cumsum<<<16, 256, 0, stream>>>(h1, agg, 64);
  k_mlp<64, 64, true, false><<<32, 256, 0, stream>>>(h1, agg, epsm, Wma, bma, Wmb, bmb, h2, nullptr, statsM);
  // BN + conv last: h2n = BN(h2); agg = cumsum(h2n); h3 = mlp + xinit
  k_cumsum_bn<<<16, 256, 0, stream>>>(h2, h2n, agg, statsM, bnmg, bnmb);
  k_mlp<64, 32, false, true><<<32, 256, 0, stream>>>(h2n, agg, epsl, Wla, bla, Wlb, blb, h3, nf, nullptr);
  // edge predictor: two passes (stats, then normalize+softmax+scatter)
  dim3 eg(128, 128);
  k_edge1<<<eg, 256, 0, stream>>>(h3, W5, b5, stats5);
  k_prep5<<<1, 64, 0, stream>>>(stats5, bn5g, bn5b, prep, ecnt);
  k_edge2<<<eg, 256, 0, stream>>>(h3, W5, b5, prep, W6, b6, out);
}

// Round 3
// 407.723 us; speedup vs baseline: 2.3642x; 2.3642x over previous
//
#include <hip/hip_runtime.h>
#include <math.h>

#define NN 2048

typedef __attribute__((ext_vector_type(8))) short short8;
typedef __attribute__((ext_vector_type(4))) float f32x4;

__device__ inline short f2bf(float x) {
  union { float f; unsigned u; } v; v.f = x;
  unsigned r = v.u + 0x7fff + ((v.u >> 16) & 1);  // RNE
  return (short)(r >> 16);
}
__device__ inline float bf2f(short h) {
  union { unsigned u; float f; } t;
  t.u = ((unsigned)(unsigned short)h) << 16;
  return t.f;
}

// ---------------------------------------------------------------------------
// Exclusive prefix-sum over node index, one wave per feature.
// ---------------------------------------------------------------------------
__global__ void k_cumsum(const float* __restrict__ X, float* __restrict__ AGG, int Fdim) {
  int lane = threadIdx.x & 63;
  int f = blockIdx.x * (blockDim.x >> 6) + (threadIdx.x >> 6);
  if (f >= Fdim) return;
  float v[32];
#pragma unroll
  for (int c = 0; c < 32; c++) v[c] = X[(size_t)(c * 64 + lane) * Fdim + f];
  float carry = 0.f;
#pragma unroll
  for (int c = 0; c < 32; c++) {
    float s = v[c];
#pragma unroll
    for (int d = 1; d < 64; d <<= 1) {
      float t = __shfl_up(s, d);
      s += (lane >= d) ? t : 0.f;
    }
    AGG[(size_t)(c * 64 + lane) * Fdim + f] = carry + (s - v[c]);
    carry += __shfl(s, 63);
  }
}

__global__ void k_cumsum_bn(const float* __restrict__ X, float* __restrict__ Y,
                            float* __restrict__ AGG, const double* __restrict__ statsM,
                            const float* __restrict__ g, const float* __restrict__ bb) {
  int lane = threadIdx.x & 63;
  int f = blockIdx.x * (blockDim.x >> 6) + (threadIdx.x >> 6);
  if (f >= 64) return;
  double mean = statsM[f] * (1.0 / 2048.0);
  double var = statsM[64 + f] * (1.0 / 2048.0) - mean * mean;
  if (var < 0.0) var = 0.0;
  float a = (float)((double)g[f] / sqrt(var + 1e-5));
  float bsh = fmaf(-(float)mean, a, bb[f]);
  float v[32];
#pragma unroll
  for (int c = 0; c < 32; c++)
    v[c] = fmaf(a, X[(size_t)(c * 64 + lane) * 64 + f], bsh);
  float carry = 0.f;
#pragma unroll
  for (int c = 0; c < 32; c++) {
    float s = v[c];
#pragma unroll
    for (int d = 1; d < 64; d <<= 1) {
      float t = __shfl_up(s, d);
      s += (lane >= d) ? t : 0.f;
    }
    Y[(size_t)(c * 64 + lane) * 64 + f] = v[c];
    AGG[(size_t)(c * 64 + lane) * 64 + f] = carry + (s - v[c]);
    carry += __shfl(s, 63);
  }
}

// ---------------------------------------------------------------------------
// Fused GIN MLP (unchanged).
// ---------------------------------------------------------------------------
template <int FIN, int FOUT, bool STATS, bool ADDX>
__global__ __launch_bounds__(256) void k_mlp(
    const float* __restrict__ X, const float* __restrict__ AGG,
    const float* __restrict__ epsp,
    const float* __restrict__ Wa, const float* __restrict__ ba,
    const float* __restrict__ Wb, const float* __restrict__ bb,
    float* __restrict__ OUT, const float* __restrict__ XINIT,
    double* __restrict__ stats) {
  __shared__ float xh[64][FIN + 1];
  __shared__ float Was[FIN][64];
  __shared__ float Ts[64][65];
  __shared__ float Wbs[64][FOUT];
  __shared__ float bas[64];
  __shared__ float bbs[FOUT];
  __shared__ float ssum[64];
  __shared__ float ssq[64];
  int tid = threadIdx.x;
  int node0 = blockIdx.x * 64;
  float ep = 1.f + epsp[0];
  for (int idx = tid; idx < 64 * FIN; idx += 256) {
    int n = idx / FIN, f = idx - n * FIN;
    size_t gidx = (size_t)(node0 + n) * FIN + f;
    xh[n][f] = fmaf(ep, X[gidx], AGG[gidx]);
  }
  for (int idx = tid; idx < FIN * 64; idx += 256) Was[idx >> 6][idx & 63] = Wa[idx];
  for (int idx = tid; idx < 64 * FOUT; idx += 256) Wbs[idx / FOUT][idx % FOUT] = Wb[idx];
  if (tid < 64) bas[tid] = ba[tid];
  if (tid < FOUT) bbs[tid] = bb[tid];
  if (STATS && tid < 64) { ssum[tid] = 0.f; ssq[tid] = 0.f; }
  __syncthreads();
  {
    int n = tid >> 2, c0 = (tid & 3) * 16;
    float acc[16];
#pragma unroll
    for (int k = 0; k < 16; k++) acc[k] = bas[c0 + k];
    for (int f = 0; f < FIN; f++) {
      float xv = xh[n][f];
#pragma unroll
      for (int k = 0; k < 16; k++) acc[k] = fmaf(xv, Was[f][c0 + k], acc[k]);
    }
#pragma unroll
    for (int k = 0; k < 16; k++) Ts[n][c0 + k] = fmaxf(acc[k], 0.f);
  }
  __syncthreads();
  {
    constexpr int CC = FOUT / 4;
    int n = tid >> 2, c0 = (tid & 3) * CC;
    float acc[CC];
#pragma unroll
    for (int k = 0; k < CC; k++) acc[k] = bbs[c0 + k];
    for (int f = 0; f < 64; f++) {
      float tv = Ts[n][f];
#pragma unroll
      for (int k = 0; k < CC; k++) acc[k] = fmaf(tv, Wbs[f][c0 + k], acc[k]);
    }
#pragma unroll
    for (int k = 0; k < CC; k++) {
      float r = fmaxf(acc[k], 0.f);
      if (STATS) {
        atomicAdd(&ssum[c0 + k], r);
        atomicAdd(&ssq[c0 + k], r * r);
      }
      if (ADDX) r += XINIT[(size_t)(node0 + n) * FOUT + c0 + k];
      OUT[(size_t)(node0 + n) * FOUT + c0 + k] = r;
    }
  }
  if (STATS) {
    __syncthreads();
    if (tid < 64) {
      atomicAdd(&stats[tid], (double)ssum[tid]);
      atomicAdd(&stats[64 + tid], (double)ssq[tid]);
    }
  }
}

// ---------------------------------------------------------------------------
// W5 [32][64] fp32 -> split bf16 W5T_hi / W5T_lo, layout [c][k] (B-operand).
// ---------------------------------------------------------------------------
__global__ void k_prepw5(const float* __restrict__ W5, short* __restrict__ W5Th,
                         short* __restrict__ W5Tl) {
  int idx = blockIdx.x * 256 + threadIdx.x;
  if (idx < 2048) {
    int c = idx >> 5, k = idx & 31;
    float wv = W5[k * 64 + c];
    short hi = f2bf(wv);
    W5Th[c * 32 + k] = hi;
    W5Tl[c * 32 + k] = f2bf(wv - bf2f(hi));
  }
}

// ---------------------------------------------------------------------------
// Tile decode: t -> (bi,bj), bi<=bj, row-major over upper triangle of 128x128.
// ---------------------------------------------------------------------------
__device__ inline void tile_decode(int t, int& bi, int& bj) {
  bi = (int)((257.0f - sqrtf(66049.0f - 8.0f * (float)t)) * 0.5f);
  if (bi > 127) bi = 127;
  while (bi > 0 && bi * (257 - bi) / 2 > t) bi--;
  while ((bi + 1) * (256 - bi) / 2 <= t) bi++;
  bj = bi + (t - bi * (257 - bi) / 2);
}

// Build split-precision A fragments for one mt row.
__device__ inline void build_afrag(const float* pI, const float* pJ,
                                   short8& ah, short8& al) {
  float4 i0 = *(const float4*)pI, i1 = *(const float4*)(pI + 4);
  float4 j0 = *(const float4*)pJ, j1 = *(const float4*)(pJ + 4);
  float m[8] = {i0.x * j0.x, i0.y * j0.y, i0.z * j0.z, i0.w * j0.w,
                i1.x * j1.x, i1.y * j1.y, i1.z * j1.z, i1.w * j1.w};
#pragma unroll
  for (int e = 0; e < 8; e++) {
    short h = f2bf(m[e]);
    ah[e] = h;
    al[e] = f2bf(m[e] - bf2f(h));
  }
}

// 3-term split-precision z = m @ W5 (error ~2^-16 relative).
__device__ inline f32x4 mfma3(short8 ah, short8 al, short8 bh, short8 bl) {
  f32x4 z = (f32x4){0.f, 0.f, 0.f, 0.f};
  z = __builtin_amdgcn_mfma_f32_16x16x32_bf16(al, bh, z, 0, 0, 0);
  z = __builtin_amdgcn_mfma_f32_16x16x32_bf16(ah, bl, z, 0, 0, 0);
  z = __builtin_amdgcn_mfma_f32_16x16x32_bf16(ah, bh, z, 0, 0, 0);
  return z;
}

// ---------------------------------------------------------------------------
// Edge pass 1 (MFMA): per-channel sum / sumsq of e = leaky(m@W5 + b5).
// ---------------------------------------------------------------------------
__global__ __launch_bounds__(256) void k_edge1m(
    const float* __restrict__ H3, const short* __restrict__ W5Th,
    const short* __restrict__ W5Tl, const float* __restrict__ b5,
    double* __restrict__ stats5, int T, int stride) {
  __shared__ float sI[16][36];
  __shared__ float sJ[16][36];
  __shared__ float ssum[64], ssq[64];
  int tid = threadIdx.x;
  int w = tid >> 6, lane = tid & 63;
  int quad = lane >> 4, l15 = lane & 15;
  int q8 = quad * 8;
  if (tid < 64) { ssum[tid] = 0.f; ssq[tid] = 0.f; }

  short8 bh[4], bl[4];
  float b5v[4];
#pragma unroll
  for (int nt = 0; nt < 4; nt++) {
    bh[nt] = *(const short8*)(W5Th + (nt * 16 + l15) * 32 + q8);
    bl[nt] = *(const short8*)(W5Tl + (nt * 16 + l15) * 32 + q8);
    b5v[nt] = b5[nt * 16 + l15];
  }
  float accS[4] = {0.f, 0.f, 0.f, 0.f}, accQ[4] = {0.f, 0.f, 0.f, 0.f};

  for (int t = blockIdx.x; t < T; t += stride) {
    int bi, bj;
    tile_decode(t, bi, bj);
    __syncthreads();
    {
      int row = tid >> 3, c4 = (tid & 7) * 4;
      int grow = (row < 16) ? (bi * 16 + row) : (bj * 16 + row - 16);
      float4 v = *(const float4*)(H3 + (size_t)grow * 32 + c4);
      float* dst = (row < 16) ? &sI[row][c4] : &sJ[row - 16][c4];
      *(float4*)dst = v;
    }
    __syncthreads();
    short8 ah[4], al[4];
#pragma unroll
    for (int mt = 0; mt < 4; mt++)
      build_afrag(&sI[4 * w + mt][q8], &sJ[l15][q8], ah[mt], al[mt]);
    bool diag = (bi == bj);
#pragma unroll
    for (int mt = 0; mt < 4; mt++) {
      int iRow = bi * 16 + 4 * w + mt;
#pragma unroll
      for (int nt = 0; nt < 4; nt++) {
        f32x4 z = mfma3(ah[mt], al[mt], bh[nt], bl[nt]);
        float bb = b5v[nt];
#pragma unroll
        for (int r = 0; r < 4; r++) {
          float zz = z[r] + bb;
          float e = fmaxf(zz, zz * 0.01f);
          if (diag) {
            int jCol = bj * 16 + quad * 4 + r;
            e = (iRow < jCol) ? e : 0.f;
          }
          accS[nt] += e;
          accQ[nt] = fmaf(e, e, accQ[nt]);
        }
      }
    }
  }
#pragma unroll
  for (int nt = 0; nt < 4; nt++) {
    accS[nt] += __shfl_xor(accS[nt], 16); accS[nt] += __shfl_xor(accS[nt], 32);
    accQ[nt] += __shfl_xor(accQ[nt], 16); accQ[nt] += __shfl_xor(accQ[nt], 32);
  }
  if (quad == 0) {
#pragma unroll
    for (int nt = 0; nt < 4; nt++) {
      atomicAdd(&ssum[nt * 16 + l15], accS[nt]);
      atomicAdd(&ssq[nt * 16 + l15], accQ[nt]);
    }
  }
  __syncthreads();
  if (tid < 64) {
    int rep = blockIdx.x & 63;
    atomicAdd(&stats5[rep * 128 + tid], (double)ssum[tid]);
    atomicAdd(&stats5[rep * 128 + 64 + tid], (double)ssq[tid]);
  }
}

__global__ void k_prep5(const double* __restrict__ stats5, const float* __restrict__ g,
                        const float* __restrict__ bb, float* __restrict__ prep, double ecnt) {
  int c = threadIdx.x;
  if (c >= 64) return;
  double s1 = 0.0, s2 = 0.0;
  for (int r = 0; r < 64; r++) {
    s1 += stats5[r * 128 + c];
    s2 += stats5[r * 128 + 64 + c];
  }
  double mean = s1 / ecnt;
  double var = s2 / ecnt - mean * mean;
  if (var < 0.0) var = 0.0;
  float a = (float)((double)g[c] / sqrt(var + 1e-5));
  prep[c] = a;
  prep[64 + c] = (float)((double)bb[c] - mean * (double)a);
}

// ---------------------------------------------------------------------------
// Edge pass 2 (MFMA): recompute z, BN + W6 + softmax, symmetric scatter.
// ---------------------------------------------------------------------------
__global__ __launch_bounds__(256) void k_edge2m(
    const float* __restrict__ H3, const short* __restrict__ W5Th,
    const short* __restrict__ W5Tl, const float* __restrict__ b5,
    const float* __restrict__ prep, const float* __restrict__ W6,
    const float* __restrict__ b6, float* __restrict__ outp, int T, int stride) {
  __shared__ float sI[16][36];
  __shared__ float sJ[16][36];
  int tid = threadIdx.x;
  int w = tid >> 6, lane = tid & 63;
  int quad = lane >> 4, l15 = lane & 15;
  int q8 = quad * 8;

  short8 bh[4], bl[4];
  float b5v[4], scv[4], shv[4], w6av[4], w6bv[4];
#pragma unroll
  for (int nt = 0; nt < 4; nt++) {
    int c = nt * 16 + l15;
    bh[nt] = *(const short8*)(W5Th + c * 32 + q8);
    bl[nt] = *(const short8*)(W5Tl + c * 32 + q8);
    b5v[nt] = b5[c];
    scv[nt] = prep[c];
    shv[nt] = prep[64 + c];
    w6av[nt] = W6[c * 2];
    w6bv[nt] = W6[c * 2 + 1];
  }
  float b60 = b6[0], b61 = b6[1];

  for (int t = blockIdx.x; t < T; t += stride) {
    int bi, bj;
    tile_decode(t, bi, bj);
    __syncthreads();
    {
      int row = tid >> 3, c4 = (tid & 7) * 4;
      int grow = (row < 16) ? (bi * 16 + row) : (bj * 16 + row - 16);
      float4 v = *(const float4*)(H3 + (size_t)grow * 32 + c4);
      float* dst = (row < 16) ? &sI[row][c4] : &sJ[row - 16][c4];
      *(float4*)dst = v;
    }
    __syncthreads();
    short8 ah[4], al[4];
#pragma unroll
    for (int mt = 0; mt < 4; mt++)
      build_afrag(&sI[4 * w + mt][q8], &sJ[l15][q8], ah[mt], al[mt]);
    f32x4 L0a[4], L1a[4];
#pragma unroll
    for (int mt = 0; mt < 4; mt++) {
      L0a[mt] = (f32x4){0.f, 0.f, 0.f, 0.f};
      L1a[mt] = (f32x4){0.f, 0.f, 0.f, 0.f};
#pragma unroll
      for (int nt = 0; nt < 4; nt++) {
        f32x4 z = mfma3(ah[mt], al[mt], bh[nt], bl[nt]);
#pragma unroll
        for (int r = 0; r < 4; r++) {
          float zz = z[r] + b5v[nt];
          float e = fmaxf(zz, zz * 0.01f);
          float en = fmaf(e, scv[nt], shv[nt]);
          L0a[mt][r] = fmaf(en, w6av[nt], L0a[mt][r]);
          L1a[mt][r] = fmaf(en, w6bv[nt], L1a[mt][r]);
        }
      }
    }
#pragma unroll
    for (int mt = 0; mt < 4; mt++) {
#pragma unroll
      for (int r = 0; r < 4; r++) {
        float a0 = L0a[mt][r], a1 = L1a[mt][r];
#pragma unroll
        for (int d = 1; d < 16; d <<= 1) {
          a0 += __shfl_xor(a0, d);
          a1 += __shfl_xor(a1, d);
        }
        if (l15 == r) {
          int i = bi * 16 + 4 * w + mt;
          int j = bj * 16 + quad * 4 + r;
          if (i < j) {
            float dlt = (a1 + b61) - (a0 + b60);
            float ex = __expf(dlt);
            float p0 = 1.f / (1.f + ex);
            float2 p = make_float2(p0, ex * p0);
            *(float2*)(outp + ((size_t)i * NN + j) * 2) = p;
            *(float2*)(outp + ((size_t)j * NN + i) * 2) = p;
          } else if (i == j) {
            *(float2*)(outp + ((size_t)i * NN + i) * 2) = make_float2(0.f, 0.f);
          }
        }
      }
    }
  }
}

// ---------------------------------------------------------------------------
extern "C" void kernel_launch(void* const* d_in, const int* in_sizes, int n_in,
                              void* d_out, int out_size, void* d_ws, size_t ws_size,
                              hipStream_t stream) {
  const float* nf   = (const float*)d_in[1];
  const float* eps1 = (const float*)d_in[2];
  const float* W1a  = (const float*)d_in[3];
  const float* b1a  = (const float*)d_in[4];
  const float* W1b  = (const float*)d_in[5];
  const float* b1b  = (const float*)d_in[6];
  const float* epsm = (const float*)d_in[7];
  const float* Wma  = (const float*)d_in[8];
  const float* bma  = (const float*)d_in[9];
  const float* Wmb  = (const float*)d_in[10];
  const float* bmb  = (const float*)d_in[11];
  const float* bnmg = (const float*)d_in[12];
  const float* bnmb = (const float*)d_in[13];
  const float* epsl = (const float*)d_in[14];
  const float* Wla  = (const float*)d_in[15];
  const float* bla  = (const float*)d_in[16];
  const float* Wlb  = (const float*)d_in[17];
  const float* blb  = (const float*)d_in[18];
  const float* W5   = (const float*)d_in[19];
  const float* b5   = (const float*)d_in[20];
  const float* bn5g = (const float*)d_in[21];
  const float* bn5b = (const float*)d_in[22];
  const float* W6   = (const float*)d_in[23];
  const float* b6   = (const float*)d_in[24];
  double ecnt = (double)in_sizes[25];
  float* out = (float*)d_out;

  float* w = (float*)d_ws;
  float* agg  = w;                         // 2048*64
  float* h1   = w + 131072;                // 2048*64
  float* h2   = w + 262144;                // 2048*64
  float* h2n  = w + 393216;                // 2048*64
  float* h3   = w + 524288;                // 2048*32
  float* prep = w + 589824;                // 128
  short* w5hi = (short*)(w + 589952);      // 2048 shorts
  short* w5lo = (short*)(w + 590976);      // 2048 shorts
  double* statsM = (double*)(w + 592000);  // 128 doubles
  double* stats5 = (double*)(w + 592256);  // 64*128 doubles

  hipMemsetAsync((void*)statsM, 0, 1024 + 65536, stream);

  k_prepw5<<<8, 256, 0, stream>>>(W5, w5hi, w5lo);
  // conv1
  k_cumsum<<<8, 256, 0, stream>>>(nf, agg, 32);
  k_mlp<32, 64, false, false><<<32, 256, 0, stream>>>(nf, agg, eps1, W1a, b1a, W1b, b1b, h1, nullptr, nullptr);
  // conv mid (+BN stats)
  k_cumsum<<<16, 256, 0, stream>>>(h1, agg, 64);
  k_mlp<64, 64, true, false><<<32, 256, 0, stream>>>(h1, agg, epsm, Wma, bma, Wmb, bmb, h2, nullptr, statsM);
  // BN + conv last
  k_cumsum_bn<<<16, 256, 0, stream>>>(h2, h2n, agg, statsM, bnmg, bnmb);
  k_mlp<64, 32, false, true><<<32, 256, 0, stream>>>(h2n, agg, epsl, Wla, bla, Wlb, blb, h3, nf, nullptr);
  // edge predictor (split-precision MFMA, grid-strided upper-tri tiles)
  const int T = 8256;        // 128*129/2 16x16 tiles
  const int NB = 2064;       // 4 tiles per block
  k_edge1m<<<NB, 256, 0, stream>>>(h3, w5hi, w5lo, b5, stats5, T, NB);
  k_prep5<<<1, 64, 0, stream>>>(stats5, bn5g, bn5b, prep, ecnt);
  k_edge2m<<<NB, 256, 0, stream>>>(h3, w5hi, w5lo, b5, prep, W6, b6, out, T, NB);
}

// Round 4
// 391.804 us; speedup vs baseline: 2.4603x; 1.0406x over previous
//
#include <hip/hip_runtime.h>
#include <hip/hip_cooperative_groups.h>
#include <math.h>

namespace cg = cooperative_groups;

#define NN 2048

typedef __attribute__((ext_vector_type(8))) short short8;
typedef __attribute__((ext_vector_type(4))) float f32x4;

__device__ inline short f2bf(float x) {
  union { float f; unsigned u; } v; v.f = x;
  unsigned r = v.u + 0x7fff + ((v.u >> 16) & 1);  // RNE
  return (short)(r >> 16);
}
__device__ inline float bf2f(short h) {
  union { unsigned u; float f; } t;
  t.u = ((unsigned)(unsigned short)h) << 16;
  return t.f;
}

// ---------------------------------------------------------------------------
// Device helpers for the fused node pipeline
// ---------------------------------------------------------------------------
__device__ void cumsum_feature(const float* __restrict__ X, float* __restrict__ AGG,
                               int Fdim, int f, int lane) {
  float v[32];
#pragma unroll
  for (int c = 0; c < 32; c++) v[c] = X[(size_t)(c * 64 + lane) * Fdim + f];
  float carry = 0.f;
#pragma unroll
  for (int c = 0; c < 32; c++) {
    float s = v[c];
#pragma unroll
    for (int d = 1; d < 64; d <<= 1) {
      float t = __shfl_up(s, d);
      s += (lane >= d) ? t : 0.f;
    }
    AGG[(size_t)(c * 64 + lane) * Fdim + f] = carry + (s - v[c]);
    carry += __shfl(s, 63);
  }
}

__device__ void cumsum_bn_feature(const float* __restrict__ X, float* __restrict__ Y,
                                  float* __restrict__ AGG, const double* __restrict__ statsM,
                                  const float* __restrict__ g, const float* __restrict__ bb,
                                  int f, int lane) {
  double mean = statsM[f] * (1.0 / 2048.0);
  double var = statsM[64 + f] * (1.0 / 2048.0) - mean * mean;
  if (var < 0.0) var = 0.0;
  float a = (float)((double)g[f] / sqrt(var + 1e-5));
  float bsh = fmaf(-(float)mean, a, bb[f]);
  float v[32];
#pragma unroll
  for (int c = 0; c < 32; c++)
    v[c] = fmaf(a, X[(size_t)(c * 64 + lane) * 64 + f], bsh);
  float carry = 0.f;
#pragma unroll
  for (int c = 0; c < 32; c++) {
    float s = v[c];
#pragma unroll
    for (int d = 1; d < 64; d <<= 1) {
      float t = __shfl_up(s, d);
      s += (lane >= d) ? t : 0.f;
    }
    Y[(size_t)(c * 64 + lane) * 64 + f] = v[c];
    AGG[(size_t)(c * 64 + lane) * 64 + f] = carry + (s - v[c]);
    carry += __shfl(s, 63);
  }
}

// GIN MLP for 64 nodes (one block), shared-memory backed.
template <int FIN, int FOUT, bool STATS, bool ADDX>
__device__ void mlp_block(float* sm, int group,
                          const float* __restrict__ X, const float* __restrict__ AGG,
                          const float* __restrict__ epsp,
                          const float* __restrict__ Wa, const float* __restrict__ ba,
                          const float* __restrict__ Wb, const float* __restrict__ bb,
                          float* __restrict__ OUT, const float* __restrict__ XINIT,
                          double* __restrict__ stats, int tid) {
  float* xh = sm;                       // 64*(FIN+1)
  float* Was = xh + 64 * (FIN + 1);     // FIN*64
  float* Ts = Was + FIN * 64;           // 64*65
  float* Wbs = Ts + 64 * 65;            // 64*FOUT
  float* bas = Wbs + 64 * FOUT;         // 64
  float* bbs = bas + 64;                // FOUT
  float* ssum = bbs + FOUT;             // 64
  float* ssq = ssum + 64;               // 64
  int node0 = group * 64;
  float ep = 1.f + epsp[0];
  for (int idx = tid; idx < 64 * FIN; idx += 256) {
    int n = idx / FIN, f = idx - n * FIN;
    size_t gidx = (size_t)(node0 + n) * FIN + f;
    xh[n * (FIN + 1) + f] = fmaf(ep, X[gidx], AGG[gidx]);
  }
  for (int idx = tid; idx < FIN * 64; idx += 256) Was[idx] = Wa[idx];
  for (int idx = tid; idx < 64 * FOUT; idx += 256) Wbs[idx] = Wb[idx];
  if (tid < 64) bas[tid] = ba[tid];
  if (tid < FOUT) bbs[tid] = bb[tid];
  if (STATS && tid < 64) { ssum[tid] = 0.f; ssq[tid] = 0.f; }
  __syncthreads();
  {
    int n = tid >> 2, c0 = (tid & 3) * 16;
    float acc[16];
#pragma unroll
    for (int k = 0; k < 16; k++) acc[k] = bas[c0 + k];
    for (int f = 0; f < FIN; f++) {
      float xv = xh[n * (FIN + 1) + f];
#pragma unroll
      for (int k = 0; k < 16; k++) acc[k] = fmaf(xv, Was[f * 64 + c0 + k], acc[k]);
    }
#pragma unroll
    for (int k = 0; k < 16; k++) Ts[n * 65 + c0 + k] = fmaxf(acc[k], 0.f);
  }
  __syncthreads();
  {
    constexpr int CC = FOUT / 4;
    int n = tid >> 2, c0 = (tid & 3) * CC;
    float acc[CC];
#pragma unroll
    for (int k = 0; k < CC; k++) acc[k] = bbs[c0 + k];
    for (int f = 0; f < 64; f++) {
      float tv = Ts[n * 65 + f];
#pragma unroll
      for (int k = 0; k < CC; k++) acc[k] = fmaf(tv, Wbs[f * FOUT + c0 + k], acc[k]);
    }
#pragma unroll
    for (int k = 0; k < CC; k++) {
      float r = fmaxf(acc[k], 0.f);
      if (STATS) {
        atomicAdd(&ssum[c0 + k], r);
        atomicAdd(&ssq[c0 + k], r * r);
      }
      if (ADDX) r += XINIT[(size_t)(node0 + n) * FOUT + c0 + k];
      OUT[(size_t)(node0 + n) * FOUT + c0 + k] = r;
    }
  }
  if (STATS) {
    __syncthreads();
    if (tid < 64) {
      atomicAdd(&stats[tid], (double)ssum[tid]);
      atomicAdd(&stats[64 + tid], (double)ssq[tid]);
    }
  }
}

// ---------------------------------------------------------------------------
// Fused node pipeline: init + prepw5 + 3x(cumsum, MLP) with grid-wide syncs.
// Launched cooperatively with 32 blocks x 256 threads.
// ---------------------------------------------------------------------------
__global__ __launch_bounds__(256) void k_node(
    const float* __restrict__ nf, const float* __restrict__ eps1,
    const float* __restrict__ W1a, const float* __restrict__ b1a,
    const float* __restrict__ W1b, const float* __restrict__ b1b,
    const float* __restrict__ epsm, const float* __restrict__ Wma,
    const float* __restrict__ bma, const float* __restrict__ Wmb,
    const float* __restrict__ bmb, const float* __restrict__ bnmg,
    const float* __restrict__ bnmb, const float* __restrict__ epsl,
    const float* __restrict__ Wla, const float* __restrict__ bla,
    const float* __restrict__ Wlb, const float* __restrict__ blb,
    const float* __restrict__ W5, float* __restrict__ agg,
    float* __restrict__ h1, float* __restrict__ h2, float* __restrict__ h2n,
    float* __restrict__ h3, short* __restrict__ w5hi, short* __restrict__ w5lo,
    double* __restrict__ statsM, double* __restrict__ stats5) {
  cg::grid_group grid = cg::this_grid();
  __shared__ float sm[16768];
  int tid = threadIdx.x;
  int blk = blockIdx.x;
  int gtid = blk * 256 + tid;
  int lane = tid & 63;
  int gw = gtid >> 6;  // global wave id, 0..127

  // phase 0: zero stats (statsM[128] + stats5[8192] contiguous) + W5 split
  for (int idx = gtid; idx < 8320; idx += 8192) statsM[idx] = 0.0;
  if (gtid < 2048) {
    int c = gtid >> 5, k = gtid & 31;
    float wv = W5[k * 64 + c];
    short hi = f2bf(wv);
    w5hi[c * 32 + k] = hi;
    w5lo[c * 32 + k] = f2bf(wv - bf2f(hi));
  }
  // phase 1: cumsum over nf (32 features)
  if (gw < 32) cumsum_feature(nf, agg, 32, gw, lane);
  grid.sync();
  // phase 2: conv1 MLP
  mlp_block<32, 64, false, false>(sm, blk, nf, agg, eps1, W1a, b1a, W1b, b1b, h1, nullptr, nullptr, tid);
  grid.sync();
  // phase 3: cumsum over h1 (64)
  if (gw < 64) cumsum_feature(h1, agg, 64, gw, lane);
  grid.sync();
  // phase 4: mid MLP (+BN stats)
  mlp_block<64, 64, true, false>(sm, blk, h1, agg, epsm, Wma, bma, Wmb, bmb, h2, nullptr, statsM, tid);
  grid.sync();
  // phase 5: BN + cumsum over h2n
  if (gw < 64) cumsum_bn_feature(h2, h2n, agg, statsM, bnmg, bnmb, gw, lane);
  grid.sync();
  // phase 6: last MLP + residual
  mlp_block<64, 32, false, true>(sm, blk, h2n, agg, epsl, Wla, bla, Wlb, blb, h3, nf, nullptr, tid);
}

// ---------------------------------------------------------------------------
// Tile decode: t -> (bi,bj), bi<=bj, row-major over upper triangle of 128x128.
// ---------------------------------------------------------------------------
__device__ inline void tile_decode(int t, int& bi, int& bj) {
  bi = (int)((257.0f - sqrtf(66049.0f - 8.0f * (float)t)) * 0.5f);
  if (bi > 127) bi = 127;
  while (bi > 0 && bi * (257 - bi) / 2 > t) bi--;
  while ((bi + 1) * (256 - bi) / 2 <= t) bi++;
  bj = bi + (t - bi * (257 - bi) / 2);
}

// Truncation-split of 8 fp32 products into hi/lo bf16 fragments, packed with
// v_perm. hi = trunc16(m) (exact residual), lo = trunc16(m - hi): total error
// ~2^-17 relative — far below the test threshold.
__device__ inline void split_pack(const float m[8], short8& ah, short8& al) {
  unsigned uh[8], ul[8];
#pragma unroll
  for (int e = 0; e < 8; e++) {
    union { float f; unsigned u; } um; um.f = m[e];
    uh[e] = um.u;
    union { unsigned u; float f; } hf; hf.u = um.u & 0xffff0000u;
    union { float f; unsigned u; } lf; lf.f = m[e] - hf.f;
    ul[e] = lf.u;
  }
  union { unsigned i[4]; short8 s; } ph, pl;
#pragma unroll
  for (int k = 0; k < 4; k++) {
    ph.i[k] = __builtin_amdgcn_perm(uh[2 * k + 1], uh[2 * k], 0x07060302u);
    pl.i[k] = __builtin_amdgcn_perm(ul[2 * k + 1], ul[2 * k], 0x07060302u);
  }
  ah = ph.s;
  al = pl.s;
}

// 3-term split-precision z = m @ W5 + bias (bias in the accumulator).
__device__ inline f32x4 mfma3b(short8 ah, short8 al, short8 bh, short8 bl, float bias) {
  f32x4 z = (f32x4){bias, bias, bias, bias};
  z = __builtin_amdgcn_mfma_f32_16x16x32_bf16(al, bh, z, 0, 0, 0);
  z = __builtin_amdgcn_mfma_f32_16x16x32_bf16(ah, bl, z, 0, 0, 0);
  z = __builtin_amdgcn_mfma_f32_16x16x32_bf16(ah, bh, z, 0, 0, 0);
  return z;
}

// ---------------------------------------------------------------------------
// Edge pass 1 (MFMA): per-channel sum / sumsq of e = leaky(m@W5 + b5).
// ---------------------------------------------------------------------------
__global__ __launch_bounds__(256) void k_edge1m(
    const float* __restrict__ H3, const short* __restrict__ W5Th,
    const short* __restrict__ W5Tl, const float* __restrict__ b5,
    double* __restrict__ stats5, int T, int stride) {
  __shared__ float sI[16][36];
  __shared__ float sJ[16][36];
  __shared__ float ssum[64], ssq[64];
  int tid = threadIdx.x;
  int w = tid >> 6, lane = tid & 63;
  int quad = lane >> 4, l15 = lane & 15;
  int q8 = quad * 8;
  if (tid < 64) { ssum[tid] = 0.f; ssq[tid] = 0.f; }

  short8 bh[4], bl[4];
  float b5v[4];
#pragma unroll
  for (int nt = 0; nt < 4; nt++) {
    bh[nt] = *(const short8*)(W5Th + (nt * 16 + l15) * 32 + q8);
    bl[nt] = *(const short8*)(W5Tl + (nt * 16 + l15) * 32 + q8);
    b5v[nt] = b5[nt * 16 + l15];
  }
  float accS[4] = {0.f, 0.f, 0.f, 0.f}, accQ[4] = {0.f, 0.f, 0.f, 0.f};

  for (int t = blockIdx.x; t < T; t += stride) {
    int bi, bj;
    tile_decode(t, bi, bj);
    __syncthreads();
    {
      int row = tid >> 3, c4 = (tid & 7) * 4;
      int grow = (row < 16) ? (bi * 16 + row) : (bj * 16 + row - 16);
      float4 v = *(const float4*)(H3 + (size_t)grow * 32 + c4);
      float* dst = (row < 16) ? &sI[row][c4] : &sJ[row - 16][c4];
      *(float4*)dst = v;
    }
    __syncthreads();
    const float* pJ = &sJ[l15][q8];
    float4 j0 = *(const float4*)pJ, j1 = *(const float4*)(pJ + 4);
    short8 ah[4], al[4];
#pragma unroll
    for (int mt = 0; mt < 4; mt++) {
      const float* pI = &sI[4 * w + mt][q8];
      float4 i0 = *(const float4*)pI, i1 = *(const float4*)(pI + 4);
      float m[8] = {i0.x * j0.x, i0.y * j0.y, i0.z * j0.z, i0.w * j0.w,
                    i1.x * j1.x, i1.y * j1.y, i1.z * j1.z, i1.w * j1.w};
      split_pack(m, ah[mt], al[mt]);
    }
    bool diag = (bi == bj);
#pragma unroll
    for (int mt = 0; mt < 4; mt++) {
      int iRow = bi * 16 + 4 * w + mt;
#pragma unroll
      for (int nt = 0; nt < 4; nt++) {
        f32x4 z = mfma3b(ah[mt], al[mt], bh[nt], bl[nt], b5v[nt]);
#pragma unroll
        for (int r = 0; r < 4; r++) {
          float e = fmaxf(z[r], z[r] * 0.01f);
          if (diag) {
            int jCol = bj * 16 + quad * 4 + r;
            e = (iRow < jCol) ? e : 0.f;
          }
          accS[nt] += e;
          accQ[nt] = fmaf(e, e, accQ[nt]);
        }
      }
    }
  }
#pragma unroll
  for (int nt = 0; nt < 4; nt++) {
    accS[nt] += __shfl_xor(accS[nt], 16); accS[nt] += __shfl_xor(accS[nt], 32);
    accQ[nt] += __shfl_xor(accQ[nt], 16); accQ[nt] += __shfl_xor(accQ[nt], 32);
  }
  if (quad == 0) {
#pragma unroll
    for (int nt = 0; nt < 4; nt++) {
      atomicAdd(&ssum[nt * 16 + l15], accS[nt]);
      atomicAdd(&ssq[nt * 16 + l15], accQ[nt]);
    }
  }
  __syncthreads();
  if (tid < 64) {
    int rep = blockIdx.x & 63;
    atomicAdd(&stats5[rep * 128 + tid], (double)ssum[tid]);
    atomicAdd(&stats5[rep * 128 + 64 + tid], (double)ssq[tid]);
  }
}

// Fold stats + BN + W6 into per-channel logit weights and base logits.
// prep[c] = sc*W6a, prep[64+c] = sc*W6b, prep[128/129] = b6 + sum(sh*W6).
__global__ void k_prep5(const double* __restrict__ stats5, const float* __restrict__ g,
                        const float* __restrict__ bb, const float* __restrict__ W6,
                        const float* __restrict__ b6, float* __restrict__ prep,
                        double ecnt) {
  __shared__ float s0s[64], s1s[64];
  int c = threadIdx.x;
  if (c < 64) {
    double s1 = 0.0, s2 = 0.0;
    for (int r = 0; r < 64; r++) {
      s1 += stats5[r * 128 + c];
      s2 += stats5[r * 128 + 64 + c];
    }
    double mean = s1 / ecnt;
    double var = s2 / ecnt - mean * mean;
    if (var < 0.0) var = 0.0;
    float a = (float)((double)g[c] / sqrt(var + 1e-5));
    float sh = (float)((double)bb[c] - mean * (double)a);
    float w6a = W6[2 * c], w6b = W6[2 * c + 1];
    prep[c] = a * w6a;
    prep[64 + c] = a * w6b;
    s0s[c] = sh * w6a;
    s1s[c] = sh * w6b;
  }
  __syncthreads();
  if (c == 0) { float t = b6[0]; for (int k = 0; k < 64; k++) t += s0s[k]; prep[128] = t; }
  if (c == 1) { float t = b6[1]; for (int k = 0; k < 64; k++) t += s1s[k]; prep[129] = t; }
}

// ---------------------------------------------------------------------------
// Edge pass 2 (MFMA): recompute z, folded BN+W6, reduce-scatter, softmax,
// symmetric scatter. One edge per lane after the reduce-scatter.
// ---------------------------------------------------------------------------
__global__ __launch_bounds__(256) void k_edge2m(
    const float* __restrict__ H3, const short* __restrict__ W5Th,
    const short* __restrict__ W5Tl, const float* __restrict__ b5,
    const float* __restrict__ prep, float* __restrict__ outp, int T, int stride) {
  __shared__ float sI[16][36];
  __shared__ float sJ[16][36];
  int tid = threadIdx.x;
  int w = tid >> 6, lane = tid & 63;
  int quad = lane >> 4, l15 = lane & 15;
  int q8 = quad * 8;

  short8 bh[4], bl[4];
  float b5v[4], sw0v[4], sw1v[4];
#pragma unroll
  for (int nt = 0; nt < 4; nt++) {
    int c = nt * 16 + l15;
    bh[nt] = *(const short8*)(W5Th + c * 32 + q8);
    bl[nt] = *(const short8*)(W5Tl + c * 32 + q8);
    b5v[nt] = b5[c];
    sw0v[nt] = prep[c];
    sw1v[nt] = prep[64 + c];
  }
  float base0 = prep[128], base1 = prep[129];

  for (int t = blockIdx.x; t < T; t += stride) {
    int bi, bj;
    tile_decode(t, bi, bj);
    __syncthreads();
    {
      int row = tid >> 3, c4 = (tid & 7) * 4;
      int grow = (row < 16) ? (bi * 16 + row) : (bj * 16 + row - 16);
      float4 v = *(const float4*)(H3 + (size_t)grow * 32 + c4);
      float* dst = (row < 16) ? &sI[row][c4] : &sJ[row - 16][c4];
      *(float4*)dst = v;
    }
    __syncthreads();
    const float* pJ = &sJ[l15][q8];
    float4 j0 = *(const float4*)pJ, j1 = *(const float4*)(pJ + 4);
    short8 ah[4], al[4];
#pragma unroll
    for (int mt = 0; mt < 4; mt++) {
      const float* pI = &sI[4 * w + mt][q8];
      float4 i0 = *(const float4*)pI, i1 = *(const float4*)(pI + 4);
      float m[8] = {i0.x * j0.x, i0.y * j0.y, i0.z * j0.z, i0.w * j0.w,
                    i1.x * j1.x, i1.y * j1.y, i1.z * j1.z, i1.w * j1.w};
      split_pack(m, ah[mt], al[mt]);
    }
    // per-lane logit partials, pair index p = mt*4+r
    float c0a[16], c1a[16];
#pragma unroll
    for (int mt = 0; mt < 4; mt++) {
#pragma unroll
      for (int nt = 0; nt < 4; nt++) {
        f32x4 z = mfma3b(ah[mt], al[mt], bh[nt], bl[nt], b5v[nt]);
#pragma unroll
        for (int r = 0; r < 4; r++) {
          float e = fmaxf(z[r], z[r] * 0.01f);
          if (nt == 0) {
            c0a[mt * 4 + r] = e * sw0v[0];
            c1a[mt * 4 + r] = e * sw1v[0];
          } else {
            c0a[mt * 4 + r] = fmaf(e, sw0v[nt], c0a[mt * 4 + r]);
            c1a[mt * 4 + r] = fmaf(e, sw1v[nt], c1a[mt * 4 + r]);
          }
        }
      }
    }
    // reduce-scatter over the 16 lanes of the quad: 30 shuffles total.
    float n0[8], n1[8];
    {
      int up = l15 & 8;
#pragma unroll
      for (int k = 0; k < 8; k++) {
        float s0 = up ? c0a[k] : c0a[8 + k];
        float s1 = up ? c1a[k] : c1a[8 + k];
        n0[k] = (up ? c0a[8 + k] : c0a[k]) + __shfl_xor(s0, 8);
        n1[k] = (up ? c1a[8 + k] : c1a[k]) + __shfl_xor(s1, 8);
      }
    }
    float q0[4], q1[4];
    {
      int up = l15 & 4;
#pragma unroll
      for (int k = 0; k < 4; k++) {
        float s0 = up ? n0[k] : n0[4 + k];
        float s1 = up ? n1[k] : n1[4 + k];
        q0[k] = (up ? n0[4 + k] : n0[k]) + __shfl_xor(s0, 4);
        q1[k] = (up ? n1[4 + k] : n1[k]) + __shfl_xor(s1, 4);
      }
    }
    float d0[2], d1[2];
    {
      int up = l15 & 2;
#pragma unroll
      for (int k = 0; k < 2; k++) {
        float s0 = up ? q0[k] : q0[2 + k];
        float s1 = up ? q1[k] : q1[2 + k];
        d0[k] = (up ? q0[2 + k] : q0[k]) + __shfl_xor(s0, 2);
        d1[k] = (up ? q1[2 + k] : q1[k]) + __shfl_xor(s1, 2);
      }
    }
    float f0, f1;
    {
      int up = l15 & 1;
      float s0 = up ? d0[0] : d0[1];
      float s1 = up ? d1[0] : d1[1];
      f0 = (up ? d0[1] : d0[0]) + __shfl_xor(s0, 1);
      f1 = (up ? d1[1] : d1[0]) + __shfl_xor(s1, 1);
    }
    // this lane owns edge (i,j)
    int i = bi * 16 + 4 * w + (l15 >> 2);
    int j = bj * 16 + quad * 4 + (l15 & 3);
    if (i < j) {
      float dlt = (f1 + base1) - (f0 + base0);
      float ex = __expf(dlt);
      float p0 = 1.f / (1.f + ex);
      float2 p = make_float2(p0, ex * p0);
      *(float2*)(outp + ((size_t)i * NN + j) * 2) = p;
      *(float2*)(outp + ((size_t)j * NN + i) * 2) = p;
    } else if (i == j) {
      *(float2*)(outp + ((size_t)i * NN + i) * 2) = make_float2(0.f, 0.f);
    }
  }
}

// ---------------------------------------------------------------------------
extern "C" void kernel_launch(void* const* d_in, const int* in_sizes, int n_in,
                              void* d_out, int out_size, void* d_ws, size_t ws_size,
                              hipStream_t stream) {
  const float* nf   = (const float*)d_in[1];
  const float* eps1 = (const float*)d_in[2];
  const float* W1a  = (const float*)d_in[3];
  const float* b1a  = (const float*)d_in[4];
  const float* W1b  = (const float*)d_in[5];
  const float* b1b  = (const float*)d_in[6];
  const float* epsm = (const float*)d_in[7];
  const float* Wma  = (const float*)d_in[8];
  const float* bma  = (const float*)d_in[9];
  const float* Wmb  = (const float*)d_in[10];
  const float* bmb  = (const float*)d_in[11];
  const float* bnmg = (const float*)d_in[12];
  const float* bnmb = (const float*)d_in[13];
  const float* epsl = (const float*)d_in[14];
  const float* Wla  = (const float*)d_in[15];
  const float* bla  = (const float*)d_in[16];
  const float* Wlb  = (const float*)d_in[17];
  const float* blb  = (const float*)d_in[18];
  const float* W5   = (const float*)d_in[19];
  const float* b5   = (const float*)d_in[20];
  const float* bn5g = (const float*)d_in[21];
  const float* bn5b = (const float*)d_in[22];
  const float* W6   = (const float*)d_in[23];
  const float* b6   = (const float*)d_in[24];
  double ecnt = (double)in_sizes[25];
  float* out = (float*)d_out;

  float* w = (float*)d_ws;
  float* agg  = w;                         // 2048*64
  float* h1   = w + 131072;                // 2048*64
  float* h2   = w + 262144;                // 2048*64
  float* h2n  = w + 393216;                // 2048*64
  float* h3   = w + 524288;                // 2048*32
  float* prep = w + 589824;                // 130 floats (pad to 192)
  short* w5hi = (short*)(w + 590016);      // 2048 shorts
  short* w5lo = (short*)(w + 591040);      // 2048 shorts
  double* statsM = (double*)(w + 592064);  // 128 doubles (+ stats5 contiguous)
  double* stats5 = statsM + 128;           // 64*128 doubles

  void* kargs[] = {
      (void*)&nf, (void*)&eps1, (void*)&W1a, (void*)&b1a, (void*)&W1b, (void*)&b1b,
      (void*)&epsm, (void*)&Wma, (void*)&bma, (void*)&Wmb, (void*)&bmb,
      (void*)&bnmg, (void*)&bnmb, (void*)&epsl, (void*)&Wla, (void*)&bla,
      (void*)&Wlb, (void*)&blb, (void*)&W5, (void*)&agg, (void*)&h1, (void*)&h2,
      (void*)&h2n, (void*)&h3, (void*)&w5hi, (void*)&w5lo, (void*)&statsM,
      (void*)&stats5};
  hipLaunchCooperativeKernel((const void*)k_node, dim3(32), dim3(256), kargs, 0, stream);

  const int T = 8256;   // 128*129/2 16x16 tiles
  const int NB = 2064;  // 4 tiles per block
  k_edge1m<<<NB, 256, 0, stream>>>(h3, w5hi, w5lo, b5, stats5, T, NB);
  k_prep5<<<1, 64, 0, stream>>>(stats5, bn5g, bn5b, W6, b6, prep, ecnt);
  k_edge2m<<<NB, 256, 0, stream>>>(h3, w5hi, w5lo, b5, prep, out, T, NB);
}

// Round 5
// 391.327 us; speedup vs baseline: 2.4633x; 1.0012x over previous
//
#include <hip/hip_runtime.h>
#include <hip/hip_cooperative_groups.h>
#include <math.h>

namespace cg = cooperative_groups;

#define NN 2048

typedef __attribute__((ext_vector_type(8))) short short8;
typedef __attribute__((ext_vector_type(4))) float f32x4;

__device__ inline short f2bf(float x) {
  union { float f; unsigned u; } v; v.f = x;
  unsigned r = v.u + 0x7fff + ((v.u >> 16) & 1);  // RNE
  return (short)(r >> 16);
}
__device__ inline float bf2f(short h) {
  union { unsigned u; float f; } t;
  t.u = ((unsigned)(unsigned short)h) << 16;
  return t.f;
}

// ---------------------------------------------------------------------------
// GIN MLP for a 32-node chunk, with fused chunk-prefix + in-chunk scan.
// xh[n][f] = (1+eps)*x[n][f] + prefix_b[f] + sum_{m<n in chunk} x[m][f]
// then OUT = relu(relu(xh@Wa+ba)@Wb+bb) (+xinit) (+BN stats).
// 256 threads; sm must hold 32*(FIN+1) + 32*65 + FIN*64 + 64*FOUT + FIN + 192+FOUT floats.
// ---------------------------------------------------------------------------
template <int FIN, int FOUT, bool STATS, bool ADDX>
__device__ void mlp32(float* sm, int blk,
                      const float* __restrict__ X, const float* __restrict__ CS,
                      const float* __restrict__ epsp,
                      const float* __restrict__ Wa, const float* __restrict__ ba,
                      const float* __restrict__ Wb, const float* __restrict__ bb,
                      float* __restrict__ OUT, const float* __restrict__ XINIT,
                      double* __restrict__ statsR, int tid) {
  float* xh = sm;                     // 32*(FIN+1)
  float* Ts = xh + 32 * (FIN + 1);    // 32*65
  float* Was = Ts + 32 * 65;          // FIN*64
  float* Wbs = Was + FIN * 64;        // 64*FOUT
  float* spref = Wbs + 64 * FOUT;     // FIN
  float* bas = spref + FIN;           // 64
  float* bbs = bas + 64;              // FOUT
  float* ssum = bbs + FOUT;           // 64
  float* ssq = ssum + 64;             // 64
  int node0 = blk * 32;
  float ep = 1.f + epsp[0];

  // x tile -> LDS (coalesced float4 reads)
  for (int idx = tid; idx < 32 * FIN / 4; idx += 256) {
    int row = idx / (FIN / 4), c4 = (idx % (FIN / 4)) * 4;
    float4 v = *(const float4*)(X + (size_t)(node0 + row) * FIN + c4);
    float* dst = xh + row * (FIN + 1) + c4;
    dst[0] = v.x; dst[1] = v.y; dst[2] = v.z; dst[3] = v.w;
  }
  // weights -> LDS
  for (int idx = tid; idx < FIN * 16; idx += 256)
    *(float4*)(Was + idx * 4) = *(const float4*)(Wa + idx * 4);
  for (int idx = tid; idx < FOUT * 16; idx += 256)
    *(float4*)(Wbs + idx * 4) = *(const float4*)(Wb + idx * 4);
  if (tid < 64) bas[tid] = ba[tid];
  if (tid < FOUT) bbs[tid] = bb[tid];
  if (STATS && tid < 64) { ssum[tid] = 0.f; ssq[tid] = 0.f; }
  // chunk prefix: sum of chunk sums below this block (independent L2-hot loads)
  if (tid < FIN) {
    float s = 0.f;
    for (int c = 0; c < blk; c++) s += CS[c * FIN + tid];
    spref[tid] = s;
  }
  __syncthreads();

  // in-chunk exclusive scan per feature column (width-32 shuffle scan)
  {
    int w = tid >> 6, lane = tid & 63, half = lane >> 5, nl = lane & 31;
#pragma unroll
    for (int p = 0; p < FIN / 8; p++) {
      int f = w * (FIN / 4) + 2 * p + half;
      float v = xh[nl * (FIN + 1) + f];
      float s = v;
#pragma unroll
      for (int d = 1; d < 32; d <<= 1) {
        float t = __shfl_up(s, (unsigned)d, 32);
        if (nl >= d) s += t;
      }
      xh[nl * (FIN + 1) + f] = fmaf(ep, v, spref[f] + (s - v));
    }
  }
  __syncthreads();

  // Phase A: T = relu(xh @ Wa + ba), Hmid=64. n = tid>>3, 8 channels/thread.
  {
    int n = tid >> 3, c0 = (tid & 7) * 8;
    float acc[8];
#pragma unroll
    for (int k = 0; k < 8; k++) acc[k] = bas[c0 + k];
    for (int f = 0; f < FIN; f++) {
      float xv = xh[n * (FIN + 1) + f];
#pragma unroll
      for (int k = 0; k < 8; k++) acc[k] = fmaf(xv, Was[f * 64 + c0 + k], acc[k]);
    }
#pragma unroll
    for (int k = 0; k < 8; k++) Ts[n * 65 + c0 + k] = fmaxf(acc[k], 0.f);
  }
  __syncthreads();

  // Phase B: OUT = relu(T @ Wb + bb) (+xinit) (+stats)
  {
    constexpr int CC = FOUT / 8;
    int n = tid >> 3, c0 = (tid & 7) * CC;
    float acc[CC];
#pragma unroll
    for (int k = 0; k < CC; k++) acc[k] = bbs[c0 + k];
    for (int f = 0; f < 64; f++) {
      float tv = Ts[n * 65 + f];
#pragma unroll
      for (int k = 0; k < CC; k++) acc[k] = fmaf(tv, Wbs[f * FOUT + c0 + k], acc[k]);
    }
#pragma unroll
    for (int k = 0; k < CC; k++) {
      float r = fmaxf(acc[k], 0.f);
      if (STATS) {
        atomicAdd(&ssum[c0 + k], r);
        atomicAdd(&ssq[c0 + k], r * r);
      }
      if (ADDX) r += XINIT[(size_t)(node0 + n) * FOUT + c0 + k];
      OUT[(size_t)(node0 + n) * FOUT + c0 + k] = r;
    }
  }
  if (STATS) {
    __syncthreads();
    if (tid < 64) {
      int rep = blk & 15;
      atomicAdd(&statsR[rep * 128 + tid], (double)ssum[tid]);
      atomicAdd(&statsR[rep * 128 + 64 + tid], (double)ssq[tid]);
    }
  }
}

// ---------------------------------------------------------------------------
// Fused node pipeline, cooperative, 64 blocks x 256 threads, 5 grid syncs.
// ---------------------------------------------------------------------------
__global__ __launch_bounds__(256) void k_node(
    const float* __restrict__ nf, const float* __restrict__ eps1,
    const float* __restrict__ W1a, const float* __restrict__ b1a,
    const float* __restrict__ W1b, const float* __restrict__ b1b,
    const float* __restrict__ epsm, const float* __restrict__ Wma,
    const float* __restrict__ bma, const float* __restrict__ Wmb,
    const float* __restrict__ bmb, const float* __restrict__ bnmg,
    const float* __restrict__ bnmb, const float* __restrict__ epsl,
    const float* __restrict__ Wla, const float* __restrict__ bla,
    const float* __restrict__ Wlb, const float* __restrict__ blb,
    const float* __restrict__ W5,
    float* __restrict__ h1, float* __restrict__ h2, float* __restrict__ h2n,
    float* __restrict__ h3, float* __restrict__ cs1, float* __restrict__ cs2,
    float* __restrict__ cs3, short* __restrict__ w5hi, short* __restrict__ w5lo,
    double* __restrict__ statsM, double* __restrict__ zbase) {
  cg::grid_group grid = cg::this_grid();
  __shared__ float sm[12800];
  int tid = threadIdx.x;
  int blk = blockIdx.x;
  int gtid = blk * 256 + tid;
  int node0 = blk * 32;

  // ---- P0: zero stats (statsM 2048 + stats5 8192 doubles, contiguous), W5 split,
  //          chunk sums of nf (F=32).
  if (gtid < 10240) zbase[gtid] = 0.0;
  if (gtid < 2048) {
    int c = gtid >> 5, k = gtid & 31;
    float wv = W5[k * 64 + c];
    short hi = f2bf(wv);
    w5hi[c * 32 + k] = hi;
    w5lo[c * 32 + k] = f2bf(wv - bf2f(hi));
  }
  {
    int f = tid & 31, g = tid >> 5;  // 8 groups x 4 nodes
    float acc = 0.f;
#pragma unroll
    for (int k = 0; k < 4; k++) acc += nf[(size_t)(node0 + g * 4 + k) * 32 + f];
    sm[g * 32 + f] = acc;
    __syncthreads();
    if (tid < 32) {
      float s = 0.f;
#pragma unroll
      for (int g2 = 0; g2 < 8; g2++) s += sm[g2 * 32 + tid];
      cs1[blk * 32 + tid] = s;
    }
  }
  grid.sync();
  // ---- P1: conv1 MLP
  mlp32<32, 64, false, false>(sm, blk, nf, cs1, eps1, W1a, b1a, W1b, b1b, h1, nullptr, nullptr, tid);
  grid.sync();
  // ---- P2: chunk sums of h1 (F=64)
  {
    int f = tid & 63, g = tid >> 6;  // 4 groups x 8 nodes
    float acc = 0.f;
#pragma unroll
    for (int k = 0; k < 8; k++) acc += h1[(size_t)(node0 + g * 8 + k) * 64 + f];
    sm[g * 64 + f] = acc;
    __syncthreads();
    if (tid < 64) cs2[blk * 64 + tid] = sm[tid] + sm[64 + tid] + sm[128 + tid] + sm[192 + tid];
  }
  grid.sync();
  // ---- P3: mid MLP (+BN stats, 16-way replicated)
  mlp32<64, 64, true, false>(sm, blk, h1, cs2, epsm, Wma, bma, Wmb, bmb, h2, nullptr, statsM, tid);
  grid.sync();
  // ---- P4: BN affine (from replicated stats) + h2n write + chunk sums of h2n
  {
    float* aff_a = sm + 512;
    float* aff_b = sm + 576;
    if (tid < 64) {
      double s1 = 0.0, s2 = 0.0;
#pragma unroll
      for (int r = 0; r < 16; r++) {
        s1 += statsM[r * 128 + tid];
        s2 += statsM[r * 128 + 64 + tid];
      }
      double mean = s1 * (1.0 / 2048.0);
      double var = s2 * (1.0 / 2048.0) - mean * mean;
      if (var < 0.0) var = 0.0;
      float a = (float)((double)bnmg[tid] / sqrt(var + 1e-5));
      aff_a[tid] = a;
      aff_b[tid] = fmaf(-(float)mean, a, bnmb[tid]);
    }
    __syncthreads();
    int f = tid & 63, g = tid >> 6;
    float a = aff_a[f], bsh = aff_b[f];
    float acc = 0.f;
#pragma unroll
    for (int k = 0; k < 8; k++) {
      size_t idx = (size_t)(node0 + g * 8 + k) * 64 + f;
      float v = fmaf(a, h2[idx], bsh);
      h2n[idx] = v;
      acc += v;
    }
    sm[g * 64 + f] = acc;
    __syncthreads();
    if (tid < 64) cs3[blk * 64 + tid] = sm[tid] + sm[64 + tid] + sm[128 + tid] + sm[192 + tid];
  }
  grid.sync();
  // ---- P5: last MLP + residual
  mlp32<64, 32, false, true>(sm, blk, h2n, cs3, epsl, Wla, bla, Wlb, blb, h3, nf, nullptr, tid);
}

// ---------------------------------------------------------------------------
// Tile decode: t -> (bi,bj), bi<=bj, row-major over upper triangle of 128x128.
// ---------------------------------------------------------------------------
__device__ inline void tile_decode(int t, int& bi, int& bj) {
  bi = (int)((257.0f - sqrtf(66049.0f - 8.0f * (float)t)) * 0.5f);
  if (bi > 127) bi = 127;
  while (bi > 0 && bi * (257 - bi) / 2 > t) bi--;
  while ((bi + 1) * (256 - bi) / 2 <= t) bi++;
  bj = bi + (t - bi * (257 - bi) / 2);
}

// Truncation-split of 8 fp32 products into hi/lo bf16 fragments, v_perm packed.
__device__ inline void split_pack(const float m[8], short8& ah, short8& al) {
  unsigned uh[8], ul[8];
#pragma unroll
  for (int e = 0; e < 8; e++) {
    union { float f; unsigned u; } um; um.f = m[e];
    uh[e] = um.u;
    union { unsigned u; float f; } hf; hf.u = um.u & 0xffff0000u;
    union { float f; unsigned u; } lf; lf.f = m[e] - hf.f;
    ul[e] = lf.u;
  }
  union { unsigned i[4]; short8 s; } ph, pl;
#pragma unroll
  for (int k = 0; k < 4; k++) {
    ph.i[k] = __builtin_amdgcn_perm(uh[2 * k + 1], uh[2 * k], 0x07060302u);
    pl.i[k] = __builtin_amdgcn_perm(ul[2 * k + 1], ul[2 * k], 0x07060302u);
  }
  ah = ph.s;
  al = pl.s;
}

// 3-term split-precision z = m @ W5 + bias (bias in the accumulator).
__device__ inline f32x4 mfma3b(short8 ah, short8 al, short8 bh, short8 bl, float bias) {
  f32x4 z = (f32x4){bias, bias, bias, bias};
  z = __builtin_amdgcn_mfma_f32_16x16x32_bf16(al, bh, z, 0, 0, 0);
  z = __builtin_amdgcn_mfma_f32_16x16x32_bf16(ah, bl, z, 0, 0, 0);
  z = __builtin_amdgcn_mfma_f32_16x16x32_bf16(ah, bh, z, 0, 0, 0);
  return z;
}

// ---------------------------------------------------------------------------
// Edge pass 1 (MFMA): per-channel sum / sumsq of e = leaky(m@W5 + b5).
// ---------------------------------------------------------------------------
__global__ __launch_bounds__(256) void k_edge1m(
    const float* __restrict__ H3, const short* __restrict__ W5Th,
    const short* __restrict__ W5Tl, const float* __restrict__ b5,
    double* __restrict__ stats5, int T, int stride) {
  __shared__ float sI[16][36];
  __shared__ float sJ[16][36];
  __shared__ float ssum[64], ssq[64];
  int tid = threadIdx.x;
  int w = tid >> 6, lane = tid & 63;
  int quad = lane >> 4, l15 = lane & 15;
  int q8 = quad * 8;
  if (tid < 64) { ssum[tid] = 0.f; ssq[tid] = 0.f; }

  short8 bh[4], bl[4];
  float b5v[4];
#pragma unroll
  for (int nt = 0; nt < 4; nt++) {
    bh[nt] = *(const short8*)(W5Th + (nt * 16 + l15) * 32 + q8);
    bl[nt] = *(const short8*)(W5Tl + (nt * 16 + l15) * 32 + q8);
    b5v[nt] = b5[nt * 16 + l15];
  }
  float accS[4] = {0.f, 0.f, 0.f, 0.f}, accQ[4] = {0.f, 0.f, 0.f, 0.f};

  for (int t = blockIdx.x; t < T; t += stride) {
    int bi, bj;
    tile_decode(t, bi, bj);
    __syncthreads();
    {
      int row = tid >> 3, c4 = (tid & 7) * 4;
      int grow = (row < 16) ? (bi * 16 + row) : (bj * 16 + row - 16);
      float4 v = *(const float4*)(H3 + (size_t)grow * 32 + c4);
      float* dst = (row < 16) ? &sI[row][c4] : &sJ[row - 16][c4];
      *(float4*)dst = v;
    }
    __syncthreads();
    const float* pJ = &sJ[l15][q8];
    float4 j0 = *(const float4*)pJ, j1 = *(const float4*)(pJ + 4);
    short8 ah[4], al[4];
#pragma unroll
    for (int mt = 0; mt < 4; mt++) {
      const float* pI = &sI[4 * w + mt][q8];
      float4 i0 = *(const float4*)pI, i1 = *(const float4*)(pI + 4);
      float m[8] = {i0.x * j0.x, i0.y * j0.y, i0.z * j0.z, i0.w * j0.w,
                    i1.x * j1.x, i1.y * j1.y, i1.z * j1.z, i1.w * j1.w};
      split_pack(m, ah[mt], al[mt]);
    }
    bool diag = (bi == bj);
#pragma unroll
    for (int mt = 0; mt < 4; mt++) {
      int iRow = bi * 16 + 4 * w + mt;
#pragma unroll
      for (int nt = 0; nt < 4; nt++) {
        f32x4 z = mfma3b(ah[mt], al[mt], bh[nt], bl[nt], b5v[nt]);
#pragma unroll
        for (int r = 0; r < 4; r++) {
          float e = fmaxf(z[r], z[r] * 0.01f);
          if (diag) {
            int jCol = bj * 16 + quad * 4 + r;
            e = (iRow < jCol) ? e : 0.f;
          }
          accS[nt] += e;
          accQ[nt] = fmaf(e, e, accQ[nt]);
        }
      }
    }
  }
#pragma unroll
  for (int nt = 0; nt < 4; nt++) {
    accS[nt] += __shfl_xor(accS[nt], 16); accS[nt] += __shfl_xor(accS[nt], 32);
    accQ[nt] += __shfl_xor(accQ[nt], 16); accQ[nt] += __shfl_xor(accQ[nt], 32);
  }
  if (quad == 0) {
#pragma unroll
    for (int nt = 0; nt < 4; nt++) {
      atomicAdd(&ssum[nt * 16 + l15], accS[nt]);
      atomicAdd(&ssq[nt * 16 + l15], accQ[nt]);
    }
  }
  __syncthreads();
  if (tid < 64) {
    int rep = blockIdx.x & 63;
    atomicAdd(&stats5[rep * 128 + tid], (double)ssum[tid]);
    atomicAdd(&stats5[rep * 128 + 64 + tid], (double)ssq[tid]);
  }
}

// Fold stats + BN + W6 into per-channel logit weights and base logits.
__global__ void k_prep5(const double* __restrict__ stats5, const float* __restrict__ g,
                        const float* __restrict__ bb, const float* __restrict__ W6,
                        const float* __restrict__ b6, float* __restrict__ prep,
                        double ecnt) {
  __shared__ float s0s[64], s1s[64];
  int c = threadIdx.x;
  if (c < 64) {
    double s1 = 0.0, s2 = 0.0;
    for (int r = 0; r < 64; r++) {
      s1 += stats5[r * 128 + c];
      s2 += stats5[r * 128 + 64 + c];
    }
    double mean = s1 / ecnt;
    double var = s2 / ecnt - mean * mean;
    if (var < 0.0) var = 0.0;
    float a = (float)((double)g[c] / sqrt(var + 1e-5));
    float sh = (float)((double)bb[c] - mean * (double)a);
    float w6a = W6[2 * c], w6b = W6[2 * c + 1];
    prep[c] = a * w6a;
    prep[64 + c] = a * w6b;
    s0s[c] = sh * w6a;
    s1s[c] = sh * w6b;
  }
  __syncthreads();
  if (c == 0) { float t = b6[0]; for (int k = 0; k < 64; k++) t += s0s[k]; prep[128] = t; }
  if (c == 1) { float t = b6[1]; for (int k = 0; k < 64; k++) t += s1s[k]; prep[129] = t; }
}

// ---------------------------------------------------------------------------
// Edge pass 2 (MFMA): recompute z, folded BN+W6, reduce-scatter, softmax,
// symmetric scatter. One edge per lane after the reduce-scatter.
// ---------------------------------------------------------------------------
__global__ __launch_bounds__(256) void k_edge2m(
    const float* __restrict__ H3, const short* __restrict__ W5Th,
    const short* __restrict__ W5Tl, const float* __restrict__ b5,
    const float* __restrict__ prep, float* __restrict__ outp, int T, int stride) {
  __shared__ float sI[16][36];
  __shared__ float sJ[16][36];
  int tid = threadIdx.x;
  int w = tid >> 6, lane = tid & 63;
  int quad = lane >> 4, l15 = lane & 15;
  int q8 = quad * 8;

  short8 bh[4], bl[4];
  float b5v[4], sw0v[4], sw1v[4];
#pragma unroll
  for (int nt = 0; nt < 4; nt++) {
    int c = nt * 16 + l15;
    bh[nt] = *(const short8*)(W5Th + c * 32 + q8);
    bl[nt] = *(const short8*)(W5Tl + c * 32 + q8);
    b5v[nt] = b5[c];
    sw0v[nt] = prep[c];
    sw1v[nt] = prep[64 + c];
  }
  float base0 = prep[128], base1 = prep[129];

  for (int t = blockIdx.x; t < T; t += stride) {
    int bi, bj;
    tile_decode(t, bi, bj);
    __syncthreads();
    {
      int row = tid >> 3, c4 = (tid & 7) * 4;
      int grow = (row < 16) ? (bi * 16 + row) : (bj * 16 + row - 16);
      float4 v = *(const float4*)(H3 + (size_t)grow * 32 + c4);
      float* dst = (row < 16) ? &sI[row][c4] : &sJ[row - 16][c4];
      *(float4*)dst = v;
    }
    __syncthreads();
    const float* pJ = &sJ[l15][q8];
    float4 j0 = *(const float4*)pJ, j1 = *(const float4*)(pJ + 4);
    short8 ah[4], al[4];
#pragma unroll
    for (int mt = 0; mt < 4; mt++) {
      const float* pI = &sI[4 * w + mt][q8];
      float4 i0 = *(const float4*)pI, i1 = *(const float4*)(pI + 4);
      float m[8] = {i0.x * j0.x, i0.y * j0.y, i0.z * j0.z, i0.w * j0.w,
                    i1.x * j1.x, i1.y * j1.y, i1.z * j1.z, i1.w * j1.w};
      split_pack(m, ah[mt], al[mt]);
    }
    float c0a[16], c1a[16];
#pragma unroll
    for (int mt = 0; mt < 4; mt++) {
#pragma unroll
      for (int nt = 0; nt < 4; nt++) {
        f32x4 z = mfma3b(ah[mt], al[mt], bh[nt], bl[nt], b5v[nt]);
#pragma unroll
        for (int r = 0; r < 4; r++) {
          float e = fmaxf(z[r], z[r] * 0.01f);
          if (nt == 0) {
            c0a[mt * 4 + r] = e * sw0v[0];
            c1a[mt * 4 + r] = e * sw1v[0];
          } else {
            c0a[mt * 4 + r] = fmaf(e, sw0v[nt], c0a[mt * 4 + r]);
            c1a[mt * 4 + r] = fmaf(e, sw1v[nt], c1a[mt * 4 + r]);
          }
        }
      }
    }
    // reduce-scatter over the 16 lanes of the quad: 30 shuffles total.
    float n0[8], n1[8];
    {
      int up = l15 & 8;
#pragma unroll
      for (int k = 0; k < 8; k++) {
        float s0 = up ? c0a[k] : c0a[8 + k];
        float s1 = up ? c1a[k] : c1a[8 + k];
        n0[k] = (up ? c0a[8 + k] : c0a[k]) + __shfl_xor(s0, 8);
        n1[k] = (up ? c1a[8 + k] : c1a[k]) + __shfl_xor(s1, 8);
      }
    }
    float q0[4], q1[4];
    {
      int up = l15 & 4;
#pragma unroll
      for (int k = 0; k < 4; k++) {
        float s0 = up ? n0[k] : n0[4 + k];
        float s1 = up ? n1[k] : n1[4 + k];
        q0[k] = (up ? n0[4 + k] : n0[k]) + __shfl_xor(s0, 4);
        q1[k] = (up ? n1[4 + k] : n1[k]) + __shfl_xor(s1, 4);
      }
    }
    float d0[2], d1[2];
    {
      int up = l15 & 2;
#pragma unroll
      for (int k = 0; k < 2; k++) {
        float s0 = up ? q0[k] : q0[2 + k];
        float s1 = up ? q1[k] : q1[2 + k];
        d0[k] = (up ? q0[2 + k] : q0[k]) + __shfl_xor(s0, 2);
        d1[k] = (up ? q1[2 + k] : q1[k]) + __shfl_xor(s1, 2);
      }
    }
    float f0, f1;
    {
      int up = l15 & 1;
      float s0 = up ? d0[0] : d0[1];
      float s1 = up ? d1[0] : d1[1];
      f0 = (up ? d0[1] : d0[0]) + __shfl_xor(s0, 1);
      f1 = (up ? d1[1] : d1[0]) + __shfl_xor(s1, 1);
    }
    int i = bi * 16 + 4 * w + (l15 >> 2);
    int j = bj * 16 + quad * 4 + (l15 & 3);
    if (i < j) {
      float dlt = (f1 + base1) - (f0 + base0);
      float ex = __expf(dlt);
      float p0 = 1.f / (1.f + ex);
      float2 p = make_float2(p0, ex * p0);
      *(float2*)(outp + ((size_t)i * NN + j) * 2) = p;
      *(float2*)(outp + ((size_t)j * NN + i) * 2) = p;
    } else if (i == j) {
      *(float2*)(outp + ((size_t)i * NN + i) * 2) = make_float2(0.f, 0.f);
    }
  }
}

// ---------------------------------------------------------------------------
extern "C" void kernel_launch(void* const* d_in, const int* in_sizes, int n_in,
                              void* d_out, int out_size, void* d_ws, size_t ws_size,
                              hipStream_t stream) {
  const float* nf   = (const float*)d_in[1];
  const float* eps1 = (const float*)d_in[2];
  const float* W1a  = (const float*)d_in[3];
  const float* b1a  = (const float*)d_in[4];
  const float* W1b  = (const float*)d_in[5];
  const float* b1b  = (const float*)d_in[6];
  const float* epsm = (const float*)d_in[7];
  const float* Wma  = (const float*)d_in[8];
  const float* bma  = (const float*)d_in[9];
  const float* Wmb  = (const float*)d_in[10];
  const float* bmb  = (const float*)d_in[11];
  const float* bnmg = (const float*)d_in[12];
  const float* bnmb = (const float*)d_in[13];
  const float* epsl = (const float*)d_in[14];
  const float* Wla  = (const float*)d_in[15];
  const float* bla  = (const float*)d_in[16];
  const float* Wlb  = (const float*)d_in[17];
  const float* blb  = (const float*)d_in[18];
  const float* W5   = (const float*)d_in[19];
  const float* b5   = (const float*)d_in[20];
  const float* bn5g = (const float*)d_in[21];
  const float* bn5b = (const float*)d_in[22];
  const float* W6   = (const float*)d_in[23];
  const float* b6   = (const float*)d_in[24];
  double ecnt = (double)in_sizes[25];
  float* out = (float*)d_out;

  float* w = (float*)d_ws;
  float* h1   = w;                         // 2048*64
  float* h2   = w + 131072;                // 2048*64
  float* h2n  = w + 262144;                // 2048*64
  float* h3   = w + 393216;                // 2048*32
  float* cs1  = w + 458752;                // 64*32
  float* cs2  = w + 460800;                // 64*64
  float* cs3  = w + 464896;                // 64*64
  float* prep = w + 468992;                // 192
  short* w5hi = (short*)(w + 469184);      // 2048 shorts
  short* w5lo = (short*)(w + 470208);      // 2048 shorts
  double* statsM = (double*)(w + 471232);  // 16*128 doubles (zbase)
  double* stats5 = statsM + 2048;          // 64*128 doubles

  void* kargs[] = {
      (void*)&nf, (void*)&eps1, (void*)&W1a, (void*)&b1a, (void*)&W1b, (void*)&b1b,
      (void*)&epsm, (void*)&Wma, (void*)&bma, (void*)&Wmb, (void*)&bmb,
      (void*)&bnmg, (void*)&bnmb, (void*)&epsl, (void*)&Wla, (void*)&bla,
      (void*)&Wlb, (void*)&blb, (void*)&W5, (void*)&h1, (void*)&h2,
      (void*)&h2n, (void*)&h3, (void*)&cs1, (void*)&cs2, (void*)&cs3,
      (void*)&w5hi, (void*)&w5lo, (void*)&statsM, (void*)&statsM};
  hipLaunchCooperativeKernel((const void*)k_node, dim3(64), dim3(256), kargs, 0, stream);

  const int T = 8256;   // 128*129/2 16x16 tiles
  const int NB = 2064;  // 4 tiles per block
  k_edge1m<<<NB, 256, 0, stream>>>(h3, w5hi, w5lo, b5, stats5, T, NB);
  k_prep5<<<1, 64, 0, stream>>>(stats5, bn5g, bn5b, W6, b6, prep, ecnt);
  k_edge2m<<<NB, 256, 0, stream>>>(h3, w5hi, w5lo, b5, prep, out, T, NB);
}

// Round 6
// 277.314 us; speedup vs baseline: 3.4760x; 1.4111x over previous
//
#include <hip/hip_runtime.h>
#include <math.h>

#define NN 2048

typedef __attribute__((ext_vector_type(8))) short short8;
typedef __attribute__((ext_vector_type(4))) float f32x4;

__device__ inline short f2bf(float x) {
  union { float f; unsigned u; } v; v.f = x;
  unsigned r = v.u + 0x7fff + ((v.u >> 16) & 1);  // RNE
  return (short)(r >> 16);
}
__device__ inline float bf2f(short h) {
  union { unsigned u; float f; } t;
  t.u = ((unsigned)(unsigned short)h) << 16;
  return t.f;
}

// ---------------------------------------------------------------------------
// Kernel A: zero stats workspace, split W5 to bf16 hi/lo, chunk-sums of nf.
// 64 blocks x 256.
// ---------------------------------------------------------------------------
__global__ __launch_bounds__(256) void k_init(
    const float* __restrict__ nf, const float* __restrict__ W5,
    float* __restrict__ cs1, short* __restrict__ w5hi, short* __restrict__ w5lo,
    double* __restrict__ zbase) {
  __shared__ float sm[256];
  int tid = threadIdx.x, blk = blockIdx.x;
  int gtid = blk * 256 + tid;
  int node0 = blk * 32;
  if (gtid < 10240) zbase[gtid] = 0.0;  // statsM(2048) + stats5(8192)
  if (gtid < 2048) {
    int c = gtid >> 5, k = gtid & 31;
    float wv = W5[k * 64 + c];
    short hi = f2bf(wv);
    w5hi[c * 32 + k] = hi;
    w5lo[c * 32 + k] = f2bf(wv - bf2f(hi));
  }
  int f = tid & 31, g = tid >> 5;  // 8 groups x 4 nodes
  float acc = 0.f;
#pragma unroll
  for (int k = 0; k < 4; k++) acc += nf[(size_t)(node0 + g * 4 + k) * 32 + f];
  sm[g * 32 + f] = acc;
  __syncthreads();
  if (tid < 32) {
    float s = 0.f;
#pragma unroll
    for (int g2 = 0; g2 < 8; g2++) s += sm[g2 * 32 + tid];
    cs1[blk * 32 + tid] = s;
  }
}

// ---------------------------------------------------------------------------
// GIN MLP kernel for a 32-node chunk: fused chunk-prefix + in-chunk scan +
// 2-layer MLP. Optional: BN-affine on input (AFFINE), BN stats out (STATS),
// chunk-sum of output (CSUM), residual add (ADDX). 64 blocks x 256.
// ---------------------------------------------------------------------------
template <int FIN, int FOUT, bool STATS, bool ADDX, bool AFFINE, bool CSUM>
__global__ __launch_bounds__(256) void k_mlp32(
    const float* __restrict__ X, const float* __restrict__ CS,
    const float* __restrict__ epsp,
    const float* __restrict__ Wa, const float* __restrict__ ba,
    const float* __restrict__ Wb, const float* __restrict__ bb,
    float* __restrict__ OUT, const float* __restrict__ XINIT,
    double* __restrict__ statsW, const double* __restrict__ statsRd,
    const float* __restrict__ bng, const float* __restrict__ bnb,
    float* __restrict__ csum) {
  __shared__ float xh[32 * (FIN + 1)];
  __shared__ float Ts[32 * 65];
  __shared__ float Was[FIN * 64];
  __shared__ float Wbs[64 * FOUT];
  __shared__ float spref[FIN];
  __shared__ float part[4 * FIN];
  __shared__ float bas[64];
  __shared__ float bbs[FOUT];
  __shared__ float ssum[64];
  __shared__ float ssq[64];
  __shared__ float affa[64];
  __shared__ float affb[64];
  int tid = threadIdx.x;
  int blk = blockIdx.x;
  int node0 = blk * 32;
  float ep = 1.f + epsp[0];

  if (AFFINE) {
    if (tid < 64) {
      double s1 = 0.0, s2 = 0.0;
#pragma unroll
      for (int r = 0; r < 16; r++) {
        s1 += statsRd[r * 128 + tid];
        s2 += statsRd[r * 128 + 64 + tid];
      }
      double mean = s1 * (1.0 / 2048.0);
      double var = s2 * (1.0 / 2048.0) - mean * mean;
      if (var < 0.0) var = 0.0;
      float a = (float)((double)bng[tid] / sqrt(var + 1e-5));
      affa[tid] = a;
      affb[tid] = fmaf(-(float)mean, a, bnb[tid]);
    }
    __syncthreads();
  }

  // x tile -> LDS (coalesced float4), affine applied on the fly if requested
  for (int idx = tid; idx < 32 * FIN / 4; idx += 256) {
    int row = idx / (FIN / 4), c4 = (idx % (FIN / 4)) * 4;
    float4 v = *(const float4*)(X + (size_t)(node0 + row) * FIN + c4);
    if (AFFINE) {
      v.x = fmaf(affa[c4 + 0], v.x, affb[c4 + 0]);
      v.y = fmaf(affa[c4 + 1], v.y, affb[c4 + 1]);
      v.z = fmaf(affa[c4 + 2], v.z, affb[c4 + 2]);
      v.w = fmaf(affa[c4 + 3], v.w, affb[c4 + 3]);
    }
    float* dst = xh + row * (FIN + 1) + c4;
    dst[0] = v.x; dst[1] = v.y; dst[2] = v.z; dst[3] = v.w;
  }
  // chunk-prefix partials: 4 threads per feature, strided over chunks < blk
  if (tid < 4 * FIN) {
    int g = tid / FIN, f = tid % FIN;
    float s = 0.f;
    for (int c = g; c < blk; c += 4) s += CS[c * FIN + f];
    part[tid] = s;
  }
  // weights -> LDS
  for (int idx = tid; idx < FIN * 16; idx += 256)
    *(float4*)(Was + idx * 4) = *(const float4*)(Wa + idx * 4);
  for (int idx = tid; idx < FOUT * 16; idx += 256)
    *(float4*)(Wbs + idx * 4) = *(const float4*)(Wb + idx * 4);
  if (tid < 64) bas[tid] = ba[tid];
  if (tid < FOUT) bbs[tid] = bb[tid];
  if ((STATS || CSUM) && tid < 64) { ssum[tid] = 0.f; ssq[tid] = 0.f; }
  __syncthreads();

  // finalize prefix (affine-transformed if needed: pref' = a*pref + 32*blk*b)
  if (tid < FIN) {
    float s = part[tid] + part[FIN + tid] + part[2 * FIN + tid] + part[3 * FIN + tid];
    if (AFFINE) s = fmaf(affa[tid], s, (float)(32 * blk) * affb[tid]);
    spref[tid] = s;
  }
  __syncthreads();

  // in-chunk exclusive scan per feature column (width-32 shuffle scan)
  {
    int w = tid >> 6, lane = tid & 63, half = lane >> 5, nl = lane & 31;
#pragma unroll
    for (int p = 0; p < FIN / 8; p++) {
      int f = w * (FIN / 4) + 2 * p + half;
      float v = xh[nl * (FIN + 1) + f];
      float s = v;
#pragma unroll
      for (int d = 1; d < 32; d <<= 1) {
        float t = __shfl_up(s, (unsigned)d, 32);
        if (nl >= d) s += t;
      }
      xh[nl * (FIN + 1) + f] = fmaf(ep, v, spref[f] + (s - v));
    }
  }
  __syncthreads();

  // Phase A: T = relu(xh @ Wa + ba), Hmid=64
  {
    int n = tid >> 3, c0 = (tid & 7) * 8;
    float acc[8];
#pragma unroll
    for (int k = 0; k < 8; k++) acc[k] = bas[c0 + k];
    for (int f = 0; f < FIN; f++) {
      float xv = xh[n * (FIN + 1) + f];
#pragma unroll
      for (int k = 0; k < 8; k++) acc[k] = fmaf(xv, Was[f * 64 + c0 + k], acc[k]);
    }
#pragma unroll
    for (int k = 0; k < 8; k++) Ts[n * 65 + c0 + k] = fmaxf(acc[k], 0.f);
  }
  __syncthreads();

  // Phase B: OUT = relu(T @ Wb + bb) (+xinit) (+stats/csum)
  {
    constexpr int CC = FOUT / 8;
    int n = tid >> 3, c0 = (tid & 7) * CC;
    float acc[CC];
#pragma unroll
    for (int k = 0; k < CC; k++) acc[k] = bbs[c0 + k];
    for (int f = 0; f < 64; f++) {
      float tv = Ts[n * 65 + f];
#pragma unroll
      for (int k = 0; k < CC; k++) acc[k] = fmaf(tv, Wbs[f * FOUT + c0 + k], acc[k]);
    }
#pragma unroll
    for (int k = 0; k < CC; k++) {
      float r = fmaxf(acc[k], 0.f);
      if (STATS || CSUM) atomicAdd(&ssum[c0 + k], r);
      if (STATS) atomicAdd(&ssq[c0 + k], r * r);
      if (ADDX) r += XINIT[(size_t)(node0 + n) * FOUT + c0 + k];
      OUT[(size_t)(node0 + n) * FOUT + c0 + k] = r;
    }
  }
  if (STATS || CSUM) {
    __syncthreads();
    if (tid < FOUT) {
      if (CSUM) csum[blk * FOUT + tid] = ssum[tid];
      if (STATS) {
        int rep = blk & 15;
        atomicAdd(&statsW[rep * 128 + tid], (double)ssum[tid]);
        atomicAdd(&statsW[rep * 128 + 64 + tid], (double)ssq[tid]);
      }
    }
  }
}

// ---------------------------------------------------------------------------
// Tile decode: t -> (bi,bj), bi<=bj, row-major over upper triangle of 128x128.
// ---------------------------------------------------------------------------
__device__ inline void tile_decode(int t, int& bi, int& bj) {
  bi = (int)((257.0f - sqrtf(66049.0f - 8.0f * (float)t)) * 0.5f);
  if (bi > 127) bi = 127;
  while (bi > 0 && bi * (257 - bi) / 2 > t) bi--;
  while ((bi + 1) * (256 - bi) / 2 <= t) bi++;
  bj = bi + (t - bi * (257 - bi) / 2);
}

// Truncation-split of 8 fp32 products into hi/lo bf16 fragments, v_perm packed.
__device__ inline void split_pack(const float m[8], short8& ah, short8& al) {
  unsigned uh[8], ul[8];
#pragma unroll
  for (int e = 0; e < 8; e++) {
    union { float f; unsigned u; } um; um.f = m[e];
    uh[e] = um.u;
    union { unsigned u; float f; } hf; hf.u = um.u & 0xffff0000u;
    union { float f; unsigned u; } lf; lf.f = m[e] - hf.f;
    ul[e] = lf.u;
  }
  union { unsigned i[4]; short8 s; } ph, pl;
#pragma unroll
  for (int k = 0; k < 4; k++) {
    ph.i[k] = __builtin_amdgcn_perm(uh[2 * k + 1], uh[2 * k], 0x07060302u);
    pl.i[k] = __builtin_amdgcn_perm(ul[2 * k + 1], ul[2 * k], 0x07060302u);
  }
  ah = ph.s;
  al = pl.s;
}

// 3-term split-precision z = m @ W5 + bias (bias in the accumulator).
__device__ inline f32x4 mfma3b(short8 ah, short8 al, short8 bh, short8 bl, float bias) {
  f32x4 z = (f32x4){bias, bias, bias, bias};
  z = __builtin_amdgcn_mfma_f32_16x16x32_bf16(al, bh, z, 0, 0, 0);
  z = __builtin_amdgcn_mfma_f32_16x16x32_bf16(ah, bl, z, 0, 0, 0);
  z = __builtin_amdgcn_mfma_f32_16x16x32_bf16(ah, bh, z, 0, 0, 0);
  return z;
}

// ---------------------------------------------------------------------------
// Edge pass 1 (MFMA): per-channel sum / sumsq of e = leaky(m@W5 + b5).
// ---------------------------------------------------------------------------
__global__ __launch_bounds__(256) void k_edge1m(
    const float* __restrict__ H3, const short* __restrict__ W5Th,
    const short* __restrict__ W5Tl, const float* __restrict__ b5,
    double* __restrict__ stats5, int T, int stride) {
  __shared__ float sI[16][36];
  __shared__ float sJ[16][36];
  __shared__ float ssum[64], ssq[64];
  int tid = threadIdx.x;
  int w = tid >> 6, lane = tid & 63;
  int quad = lane >> 4, l15 = lane & 15;
  int q8 = quad * 8;
  if (tid < 64) { ssum[tid] = 0.f; ssq[tid] = 0.f; }

  short8 bh[4], bl[4];
  float b5v[4];
#pragma unroll
  for (int nt = 0; nt < 4; nt++) {
    bh[nt] = *(const short8*)(W5Th + (nt * 16 + l15) * 32 + q8);
    bl[nt] = *(const short8*)(W5Tl + (nt * 16 + l15) * 32 + q8);
    b5v[nt] = b5[nt * 16 + l15];
  }
  float accS[4] = {0.f, 0.f, 0.f, 0.f}, accQ[4] = {0.f, 0.f, 0.f, 0.f};

  for (int t = blockIdx.x; t < T; t += stride) {
    int bi, bj;
    tile_decode(t, bi, bj);
    __syncthreads();
    {
      int row = tid >> 3, c4 = (tid & 7) * 4;
      int grow = (row < 16) ? (bi * 16 + row) : (bj * 16 + row - 16);
      float4 v = *(const float4*)(H3 + (size_t)grow * 32 + c4);
      float* dst = (row < 16) ? &sI[row][c4] : &sJ[row - 16][c4];
      *(float4*)dst = v;
    }
    __syncthreads();
    const float* pJ = &sJ[l15][q8];
    float4 j0 = *(const float4*)pJ, j1 = *(const float4*)(pJ + 4);
    short8 ah[4], al[4];
#pragma unroll
    for (int mt = 0; mt < 4; mt++) {
      const float* pI = &sI[4 * w + mt][q8];
      float4 i0 = *(const float4*)pI, i1 = *(const float4*)(pI + 4);
      float m[8] = {i0.x * j0.x, i0.y * j0.y, i0.z * j0.z, i0.w * j0.w,
                    i1.x * j1.x, i1.y * j1.y, i1.z * j1.z, i1.w * j1.w};
      split_pack(m, ah[mt], al[mt]);
    }
    bool diag = (bi == bj);
#pragma unroll
    for (int mt = 0; mt < 4; mt++) {
      int iRow = bi * 16 + 4 * w + mt;
#pragma unroll
      for (int nt = 0; nt < 4; nt++) {
        f32x4 z = mfma3b(ah[mt], al[mt], bh[nt], bl[nt], b5v[nt]);
#pragma unroll
        for (int r = 0; r < 4; r++) {
          float e = fmaxf(z[r], z[r] * 0.01f);
          if (diag) {
            int jCol = bj * 16 + quad * 4 + r;
            e = (iRow < jCol) ? e : 0.f;
          }
          accS[nt] += e;
          accQ[nt] = fmaf(e, e, accQ[nt]);
        }
      }
    }
  }
#pragma unroll
  for (int nt = 0; nt < 4; nt++) {
    accS[nt] += __shfl_xor(accS[nt], 16); accS[nt] += __shfl_xor(accS[nt], 32);
    accQ[nt] += __shfl_xor(accQ[nt], 16); accQ[nt] += __shfl_xor(accQ[nt], 32);
  }
  if (quad == 0) {
#pragma unroll
    for (int nt = 0; nt < 4; nt++) {
      atomicAdd(&ssum[nt * 16 + l15], accS[nt]);
      atomicAdd(&ssq[nt * 16 + l15], accQ[nt]);
    }
  }
  __syncthreads();
  if (tid < 64) {
    int rep = blockIdx.x & 63;
    atomicAdd(&stats5[rep * 128 + tid], (double)ssum[tid]);
    atomicAdd(&stats5[rep * 128 + 64 + tid], (double)ssq[tid]);
  }
}

// Fold stats + BN + W6 into per-channel logit weights and base logits.
__global__ void k_prep5(const double* __restrict__ stats5, const float* __restrict__ g,
                        const float* __restrict__ bb, const float* __restrict__ W6,
                        const float* __restrict__ b6, float* __restrict__ prep,
                        double ecnt) {
  __shared__ float s0s[64], s1s[64];
  int c = threadIdx.x;
  if (c < 64) {
    double s1 = 0.0, s2 = 0.0;
    for (int r = 0; r < 64; r++) {
      s1 += stats5[r * 128 + c];
      s2 += stats5[r * 128 + 64 + c];
    }
    double mean = s1 / ecnt;
    double var = s2 / ecnt - mean * mean;
    if (var < 0.0) var = 0.0;
    float a = (float)((double)g[c] / sqrt(var + 1e-5));
    float sh = (float)((double)bb[c] - mean * (double)a);
    float w6a = W6[2 * c], w6b = W6[2 * c + 1];
    prep[c] = a * w6a;
    prep[64 + c] = a * w6b;
    s0s[c] = sh * w6a;
    s1s[c] = sh * w6b;
  }
  __syncthreads();
  if (c == 0) { float t = b6[0]; for (int k = 0; k < 64; k++) t += s0s[k]; prep[128] = t; }
  if (c == 1) { float t = b6[1]; for (int k = 0; k < 64; k++) t += s1s[k]; prep[129] = t; }
}

// ---------------------------------------------------------------------------
// Edge pass 2 (MFMA): recompute z, folded BN+W6, reduce-scatter, softmax,
// symmetric scatter. One edge per lane after the reduce-scatter.
// ---------------------------------------------------------------------------
__global__ __launch_bounds__(256) void k_edge2m(
    const float* __restrict__ H3, const short* __restrict__ W5Th,
    const short* __restrict__ W5Tl, const float* __restrict__ b5,
    const float* __restrict__ prep, float* __restrict__ outp, int T, int stride) {
  __shared__ float sI[16][36];
  __shared__ float sJ[16][36];
  int tid = threadIdx.x;
  int w = tid >> 6, lane = tid & 63;
  int quad = lane >> 4, l15 = lane & 15;
  int q8 = quad * 8;

  short8 bh[4], bl[4];
  float b5v[4], sw0v[4], sw1v[4];
#pragma unroll
  for (int nt = 0; nt < 4; nt++) {
    int c = nt * 16 + l15;
    bh[nt] = *(const short8*)(W5Th + c * 32 + q8);
    bl[nt] = *(const short8*)(W5Tl + c * 32 + q8);
    b5v[nt] = b5[c];
    sw0v[nt] = prep[c];
    sw1v[nt] = prep[64 + c];
  }
  float base0 = prep[128], base1 = prep[129];

  for (int t = blockIdx.x; t < T; t += stride) {
    int bi, bj;
    tile_decode(t, bi, bj);
    __syncthreads();
    {
      int row = tid >> 3, c4 = (tid & 7) * 4;
      int grow = (row < 16) ? (bi * 16 + row) : (bj * 16 + row - 16);
      float4 v = *(const float4*)(H3 + (size_t)grow * 32 + c4);
      float* dst = (row < 16) ? &sI[row][c4] : &sJ[row - 16][c4];
      *(float4*)dst = v;
    }
    __syncthreads();
    const float* pJ = &sJ[l15][q8];
    float4 j0 = *(const float4*)pJ, j1 = *(const float4*)(pJ + 4);
    short8 ah[4], al[4];
#pragma unroll
    for (int mt = 0; mt < 4; mt++) {
      const float* pI = &sI[4 * w + mt][q8];
      float4 i0 = *(const float4*)pI, i1 = *(const float4*)(pI + 4);
      float m[8] = {i0.x * j0.x, i0.y * j0.y, i0.z * j0.z, i0.w * j0.w,
                    i1.x * j1.x, i1.y * j1.y, i1.z * j1.z, i1.w * j1.w};
      split_pack(m, ah[mt], al[mt]);
    }
    float c0a[16], c1a[16];
#pragma unroll
    for (int mt = 0; mt < 4; mt++) {
#pragma unroll
      for (int nt = 0; nt < 4; nt++) {
        f32x4 z = mfma3b(ah[mt], al[mt], bh[nt], bl[nt], b5v[nt]);
#pragma unroll
        for (int r = 0; r < 4; r++) {
          float e = fmaxf(z[r], z[r] * 0.01f);
          if (nt == 0) {
            c0a[mt * 4 + r] = e * sw0v[0];
            c1a[mt * 4 + r] = e * sw1v[0];
          } else {
            c0a[mt * 4 + r] = fmaf(e, sw0v[nt], c0a[mt * 4 + r]);
            c1a[mt * 4 + r] = fmaf(e, sw1v[nt], c1a[mt * 4 + r]);
          }
        }
      }
    }
    // reduce-scatter over the 16 lanes of the quad: 30 shuffles total.
    float n0[8], n1[8];
    {
      int up = l15 & 8;
#pragma unroll
      for (int k = 0; k < 8; k++) {
        float s0 = up ? c0a[k] : c0a[8 + k];
        float s1 = up ? c1a[k] : c1a[8 + k];
        n0[k] = (up ? c0a[8 + k] : c0a[k]) + __shfl_xor(s0, 8);
        n1[k] = (up ? c1a[8 + k] : c1a[k]) + __shfl_xor(s1, 8);
      }
    }
    float q0[4], q1[4];
    {
      int up = l15 & 4;
#pragma unroll
      for (int k = 0; k < 4; k++) {
        float s0 = up ? n0[k] : n0[4 + k];
        float s1 = up ? n1[k] : n1[4 + k];
        q0[k] = (up ? n0[4 + k] : n0[k]) + __shfl_xor(s0, 4);
        q1[k] = (up ? n1[4 + k] : n1[k]) + __shfl_xor(s1, 4);
      }
    }
    float d0[2], d1[2];
    {
      int up = l15 & 2;
#pragma unroll
      for (int k = 0; k < 2; k++) {
        float s0 = up ? q0[k] : q0[2 + k];
        float s1 = up ? q1[k] : q1[2 + k];
        d0[k] = (up ? q0[2 + k] : q0[k]) + __shfl_xor(s0, 2);
        d1[k] = (up ? q1[2 + k] : q1[k]) + __shfl_xor(s1, 2);
      }
    }
    float f0, f1;
    {
      int up = l15 & 1;
      float s0 = up ? d0[0] : d0[1];
      float s1 = up ? d1[0] : d1[1];
      f0 = (up ? d0[1] : d0[0]) + __shfl_xor(s0, 1);
      f1 = (up ? d1[1] : d1[0]) + __shfl_xor(s1, 1);
    }
    int i = bi * 16 + 4 * w + (l15 >> 2);
    int j = bj * 16 + quad * 4 + (l15 & 3);
    if (i < j) {
      float dlt = (f1 + base1) - (f0 + base0);
      float ex = __expf(dlt);
      float p0 = 1.f / (1.f + ex);
      float2 p = make_float2(p0, ex * p0);
      *(float2*)(outp + ((size_t)i * NN + j) * 2) = p;
      *(float2*)(outp + ((size_t)j * NN + i) * 2) = p;
    } else if (i == j) {
      *(float2*)(outp + ((size_t)i * NN + i) * 2) = make_float2(0.f, 0.f);
    }
  }
}

// ---------------------------------------------------------------------------
extern "C" void kernel_launch(void* const* d_in, const int* in_sizes, int n_in,
                              void* d_out, int out_size, void* d_ws, size_t ws_size,
                              hipStream_t stream) {
  const float* nf   = (const float*)d_in[1];
  const float* eps1 = (const float*)d_in[2];
  const float* W1a  = (const float*)d_in[3];
  const float* b1a  = (const float*)d_in[4];
  const float* W1b  = (const float*)d_in[5];
  const float* b1b  = (const float*)d_in[6];
  const float* epsm = (const float*)d_in[7];
  const float* Wma  = (const float*)d_in[8];
  const float* bma  = (const float*)d_in[9];
  const float* Wmb  = (const float*)d_in[10];
  const float* bmb  = (const float*)d_in[11];
  const float* bnmg = (const float*)d_in[12];
  const float* bnmb = (const float*)d_in[13];
  const float* epsl = (const float*)d_in[14];
  const float* Wla  = (const float*)d_in[15];
  const float* bla  = (const float*)d_in[16];
  const float* Wlb  = (const float*)d_in[17];
  const float* blb  = (const float*)d_in[18];
  const float* W5   = (const float*)d_in[19];
  const float* b5   = (const float*)d_in[20];
  const float* bn5g = (const float*)d_in[21];
  const float* bn5b = (const float*)d_in[22];
  const float* W6   = (const float*)d_in[23];
  const float* b6   = (const float*)d_in[24];
  double ecnt = (double)in_sizes[25];
  float* out = (float*)d_out;

  float* w = (float*)d_ws;
  float* h1   = w;                         // 2048*64
  float* h2   = w + 131072;                // 2048*64
  float* h3   = w + 262144;                // 2048*32
  float* cs1  = w + 327680;                // 64*32
  float* cs2  = w + 329728;                // 64*64
  float* csr  = w + 333824;                // 64*64 (raw h2 chunk sums)
  float* prep = w + 337920;                // 192
  short* w5hi = (short*)(w + 338112);      // 2048 shorts
  short* w5lo = (short*)(w + 339136);      // 2048 shorts
  double* statsM = (double*)(w + 340160);  // 2048 doubles (16-rep stats)
  double* stats5 = statsM + 2048;          // 64*128 doubles

  // node pipeline: 4 flat kernels (kernel boundary = device-wide barrier)
  k_init<<<64, 256, 0, stream>>>(nf, W5, cs1, w5hi, w5lo, statsM);
  k_mlp32<32, 64, false, false, false, true><<<64, 256, 0, stream>>>(
      nf, cs1, eps1, W1a, b1a, W1b, b1b, h1, nullptr, nullptr, nullptr,
      nullptr, nullptr, cs2);
  k_mlp32<64, 64, true, false, false, true><<<64, 256, 0, stream>>>(
      h1, cs2, epsm, Wma, bma, Wmb, bmb, h2, nullptr, statsM, nullptr,
      nullptr, nullptr, csr);
  k_mlp32<64, 32, false, true, true, false><<<64, 256, 0, stream>>>(
      h2, csr, epsl, Wla, bla, Wlb, blb, h3, nf, nullptr, statsM,
      bnmg, bnmb, nullptr);

  // edge predictor
  const int T = 8256;   // 128*129/2 16x16 tiles
  const int NB = 2064;  // 4 tiles per block
  k_edge1m<<<NB, 256, 0, stream>>>(h3, w5hi, w5lo, b5, stats5, T, NB);
  k_prep5<<<1, 64, 0, stream>>>(stats5, bn5g, bn5b, W6, b6, prep, ecnt);
  k_edge2m<<<NB, 256, 0, stream>>>(h3, w5hi, w5lo, b5, prep, out, T, NB);
}

// Round 7
// 255.347 us; speedup vs baseline: 3.7751x; 1.0860x over previous
//
#include <hip/hip_runtime.h>
#include <math.h>

#define NN 2048

typedef __attribute__((ext_vector_type(8))) short short8;
typedef __attribute__((ext_vector_type(4))) float f32x4;

__device__ inline short f2bf(float x) {
  union { float f; unsigned u; } v; v.f = x;
  unsigned r = v.u + 0x7fff + ((v.u >> 16) & 1);  // RNE
  return (short)(r >> 16);
}
__device__ inline float bf2f(short h) {
  union { unsigned u; float f; } t;
  t.u = ((unsigned)(unsigned short)h) << 16;
  return t.f;
}

// ---------------------------------------------------------------------------
// Kernel A: zero stats workspace, split W5 to bf16 hi/lo, chunk-sums of nf.
// ---------------------------------------------------------------------------
__global__ __launch_bounds__(256) void k_init(
    const float* __restrict__ nf, const float* __restrict__ W5,
    float* __restrict__ cs1, short* __restrict__ w5hi, short* __restrict__ w5lo,
    double* __restrict__ zbase) {
  __shared__ float sm[256];
  int tid = threadIdx.x, blk = blockIdx.x;
  int gtid = blk * 256 + tid;
  int node0 = blk * 32;
  if (gtid < 10240) zbase[gtid] = 0.0;  // statsM(2048) + stats5(8192)
  if (gtid < 2048) {
    int c = gtid >> 5, k = gtid & 31;
    float wv = W5[k * 64 + c];
    short hi = f2bf(wv);
    w5hi[c * 32 + k] = hi;
    w5lo[c * 32 + k] = f2bf(wv - bf2f(hi));
  }
  int f = tid & 31, g = tid >> 5;
  float acc = 0.f;
#pragma unroll
  for (int k = 0; k < 4; k++) acc += nf[(size_t)(node0 + g * 4 + k) * 32 + f];
  sm[g * 32 + f] = acc;
  __syncthreads();
  if (tid < 32) {
    float s = 0.f;
#pragma unroll
    for (int g2 = 0; g2 < 8; g2++) s += sm[g2 * 32 + tid];
    cs1[blk * 32 + tid] = s;
  }
}

// ---------------------------------------------------------------------------
// GIN MLP kernel for a 32-node chunk (unchanged from R6).
// ---------------------------------------------------------------------------
template <int FIN, int FOUT, bool STATS, bool ADDX, bool AFFINE, bool CSUM>
__global__ __launch_bounds__(256) void k_mlp32(
    const float* __restrict__ X, const float* __restrict__ CS,
    const float* __restrict__ epsp,
    const float* __restrict__ Wa, const float* __restrict__ ba,
    const float* __restrict__ Wb, const float* __restrict__ bb,
    float* __restrict__ OUT, const float* __restrict__ XINIT,
    double* __restrict__ statsW, const double* __restrict__ statsRd,
    const float* __restrict__ bng, const float* __restrict__ bnb,
    float* __restrict__ csum) {
  __shared__ float xh[32 * (FIN + 1)];
  __shared__ float Ts[32 * 65];
  __shared__ float Was[FIN * 64];
  __shared__ float Wbs[64 * FOUT];
  __shared__ float spref[FIN];
  __shared__ float part[4 * FIN];
  __shared__ float bas[64];
  __shared__ float bbs[FOUT];
  __shared__ float ssum[64];
  __shared__ float ssq[64];
  __shared__ float affa[64];
  __shared__ float affb[64];
  int tid = threadIdx.x;
  int blk = blockIdx.x;
  int node0 = blk * 32;
  float ep = 1.f + epsp[0];

  if (AFFINE) {
    if (tid < 64) {
      double s1 = 0.0, s2 = 0.0;
#pragma unroll
      for (int r = 0; r < 16; r++) {
        s1 += statsRd[r * 128 + tid];
        s2 += statsRd[r * 128 + 64 + tid];
      }
      double mean = s1 * (1.0 / 2048.0);
      double var = s2 * (1.0 / 2048.0) - mean * mean;
      if (var < 0.0) var = 0.0;
      float a = (float)((double)bng[tid] / sqrt(var + 1e-5));
      affa[tid] = a;
      affb[tid] = fmaf(-(float)mean, a, bnb[tid]);
    }
    __syncthreads();
  }

  for (int idx = tid; idx < 32 * FIN / 4; idx += 256) {
    int row = idx / (FIN / 4), c4 = (idx % (FIN / 4)) * 4;
    float4 v = *(const float4*)(X + (size_t)(node0 + row) * FIN + c4);
    if (AFFINE) {
      v.x = fmaf(affa[c4 + 0], v.x, affb[c4 + 0]);
      v.y = fmaf(affa[c4 + 1], v.y, affb[c4 + 1]);
      v.z = fmaf(affa[c4 + 2], v.z, affb[c4 + 2]);
      v.w = fmaf(affa[c4 + 3], v.w, affb[c4 + 3]);
    }
    float* dst = xh + row * (FIN + 1) + c4;
    dst[0] = v.x; dst[1] = v.y; dst[2] = v.z; dst[3] = v.w;
  }
  if (tid < 4 * FIN) {
    int g = tid / FIN, f = tid % FIN;
    float s = 0.f;
    for (int c = g; c < blk; c += 4) s += CS[c * FIN + f];
    part[tid] = s;
  }
  for (int idx = tid; idx < FIN * 16; idx += 256)
    *(float4*)(Was + idx * 4) = *(const float4*)(Wa + idx * 4);
  for (int idx = tid; idx < FOUT * 16; idx += 256)
    *(float4*)(Wbs + idx * 4) = *(const float4*)(Wb + idx * 4);
  if (tid < 64) bas[tid] = ba[tid];
  if (tid < FOUT) bbs[tid] = bb[tid];
  if ((STATS || CSUM) && tid < 64) { ssum[tid] = 0.f; ssq[tid] = 0.f; }
  __syncthreads();

  if (tid < FIN) {
    float s = part[tid] + part[FIN + tid] + part[2 * FIN + tid] + part[3 * FIN + tid];
    if (AFFINE) s = fmaf(affa[tid], s, (float)(32 * blk) * affb[tid]);
    spref[tid] = s;
  }
  __syncthreads();

  {
    int w = tid >> 6, lane = tid & 63, half = lane >> 5, nl = lane & 31;
#pragma unroll
    for (int p = 0; p < FIN / 8; p++) {
      int f = w * (FIN / 4) + 2 * p + half;
      float v = xh[nl * (FIN + 1) + f];
      float s = v;
#pragma unroll
      for (int d = 1; d < 32; d <<= 1) {
        float t = __shfl_up(s, (unsigned)d, 32);
        if (nl >= d) s += t;
      }
      xh[nl * (FIN + 1) + f] = fmaf(ep, v, spref[f] + (s - v));
    }
  }
  __syncthreads();

  {
    int n = tid >> 3, c0 = (tid & 7) * 8;
    float acc[8];
#pragma unroll
    for (int k = 0; k < 8; k++) acc[k] = bas[c0 + k];
    for (int f = 0; f < FIN; f++) {
      float xv = xh[n * (FIN + 1) + f];
#pragma unroll
      for (int k = 0; k < 8; k++) acc[k] = fmaf(xv, Was[f * 64 + c0 + k], acc[k]);
    }
#pragma unroll
    for (int k = 0; k < 8; k++) Ts[n * 65 + c0 + k] = fmaxf(acc[k], 0.f);
  }
  __syncthreads();

  {
    constexpr int CC = FOUT / 8;
    int n = tid >> 3, c0 = (tid & 7) * CC;
    float acc[CC];
#pragma unroll
    for (int k = 0; k < CC; k++) acc[k] = bbs[c0 + k];
    for (int f = 0; f < 64; f++) {
      float tv = Ts[n * 65 + f];
#pragma unroll
      for (int k = 0; k < CC; k++) acc[k] = fmaf(tv, Wbs[f * FOUT + c0 + k], acc[k]);
    }
#pragma unroll
    for (int k = 0; k < CC; k++) {
      float r = fmaxf(acc[k], 0.f);
      if (STATS || CSUM) atomicAdd(&ssum[c0 + k], r);
      if (STATS) atomicAdd(&ssq[c0 + k], r * r);
      if (ADDX) r += XINIT[(size_t)(node0 + n) * FOUT + c0 + k];
      OUT[(size_t)(node0 + n) * FOUT + c0 + k] = r;
    }
  }
  if (STATS || CSUM) {
    __syncthreads();
    if (tid < FOUT) {
      if (CSUM) csum[blk * FOUT + tid] = ssum[tid];
      if (STATS) {
        int rep = blk & 15;
        atomicAdd(&statsW[rep * 128 + tid], (double)ssum[tid]);
        atomicAdd(&statsW[rep * 128 + 64 + tid], (double)ssq[tid]);
      }
    }
  }
}

// ---------------------------------------------------------------------------
// Tile decode: t -> (bi,bj), bi<=bj, row-major over upper triangle of 128x128.
// ---------------------------------------------------------------------------
__device__ inline void tile_decode(int t, int& bi, int& bj) {
  bi = (int)((257.0f - sqrtf(66049.0f - 8.0f * (float)t)) * 0.5f);
  if (bi > 127) bi = 127;
  while (bi > 0 && bi * (257 - bi) / 2 > t) bi--;
  while ((bi + 1) * (256 - bi) / 2 <= t) bi++;
  bj = bi + (t - bi * (257 - bi) / 2);
}

// Truncation-split of 8 fp32 products into hi/lo bf16 fragments, v_perm packed.
__device__ inline void split_pack(const float m[8], short8& ah, short8& al) {
  unsigned uh[8], ul[8];
#pragma unroll
  for (int e = 0; e < 8; e++) {
    union { float f; unsigned u; } um; um.f = m[e];
    uh[e] = um.u;
    union { unsigned u; float f; } hf; hf.u = um.u & 0xffff0000u;
    union { float f; unsigned u; } lf; lf.f = m[e] - hf.f;
    ul[e] = lf.u;
  }
  union { unsigned i[4]; short8 s; } ph, pl;
#pragma unroll
  for (int k = 0; k < 4; k++) {
    ph.i[k] = __builtin_amdgcn_perm(uh[2 * k + 1], uh[2 * k], 0x07060302u);
    pl.i[k] = __builtin_amdgcn_perm(ul[2 * k + 1], ul[2 * k], 0x07060302u);
  }
  ah = ph.s;
  al = pl.s;
}

// 3-term split-precision z = m @ W5 + bias (bias in the accumulator).
__device__ inline f32x4 mfma3b(short8 ah, short8 al, short8 bh, short8 bl, float bias) {
  f32x4 z = (f32x4){bias, bias, bias, bias};
  z = __builtin_amdgcn_mfma_f32_16x16x32_bf16(al, bh, z, 0, 0, 0);
  z = __builtin_amdgcn_mfma_f32_16x16x32_bf16(ah, bl, z, 0, 0, 0);
  z = __builtin_amdgcn_mfma_f32_16x16x32_bf16(ah, bh, z, 0, 0, 0);
  return z;
}

// ---------------------------------------------------------------------------
// Edge pass 1 (MFMA): per-channel sum / sumsq of e = leaky(m@W5 + b5).
// (unchanged from R6)
// ---------------------------------------------------------------------------
__global__ __launch_bounds__(256) void k_edge1m(
    const float* __restrict__ H3, const short* __restrict__ W5Th,
    const short* __restrict__ W5Tl, const float* __restrict__ b5,
    double* __restrict__ stats5, int T, int stride) {
  __shared__ float sI[16][36];
  __shared__ float sJ[16][36];
  __shared__ float ssum[64], ssq[64];
  int tid = threadIdx.x;
  int w = tid >> 6, lane = tid & 63;
  int quad = lane >> 4, l15 = lane & 15;
  int q8 = quad * 8;
  if (tid < 64) { ssum[tid] = 0.f; ssq[tid] = 0.f; }

  short8 bh[4], bl[4];
  float b5v[4];
#pragma unroll
  for (int nt = 0; nt < 4; nt++) {
    bh[nt] = *(const short8*)(W5Th + (nt * 16 + l15) * 32 + q8);
    bl[nt] = *(const short8*)(W5Tl + (nt * 16 + l15) * 32 + q8);
    b5v[nt] = b5[nt * 16 + l15];
  }
  float accS[4] = {0.f, 0.f, 0.f, 0.f}, accQ[4] = {0.f, 0.f, 0.f, 0.f};

  for (int t = blockIdx.x; t < T; t += stride) {
    int bi, bj;
    tile_decode(t, bi, bj);
    __syncthreads();
    {
      int row = tid >> 3, c4 = (tid & 7) * 4;
      int grow = (row < 16) ? (bi * 16 + row) : (bj * 16 + row - 16);
      float4 v = *(const float4*)(H3 + (size_t)grow * 32 + c4);
      float* dst = (row < 16) ? &sI[row][c4] : &sJ[row - 16][c4];
      *(float4*)dst = v;
    }
    __syncthreads();
    const float* pJ = &sJ[l15][q8];
    float4 j0 = *(const float4*)pJ, j1 = *(const float4*)(pJ + 4);
    short8 ah[4], al[4];
#pragma unroll
    for (int mt = 0; mt < 4; mt++) {
      const float* pI = &sI[4 * w + mt][q8];
      float4 i0 = *(const float4*)pI, i1 = *(const float4*)(pI + 4);
      float m[8] = {i0.x * j0.x, i0.y * j0.y, i0.z * j0.z, i0.w * j0.w,
                    i1.x * j1.x, i1.y * j1.y, i1.z * j1.z, i1.w * j1.w};
      split_pack(m, ah[mt], al[mt]);
    }
    bool diag = (bi == bj);
#pragma unroll
    for (int mt = 0; mt < 4; mt++) {
      int iRow = bi * 16 + 4 * w + mt;
#pragma unroll
      for (int nt = 0; nt < 4; nt++) {
        f32x4 z = mfma3b(ah[mt], al[mt], bh[nt], bl[nt], b5v[nt]);
#pragma unroll
        for (int r = 0; r < 4; r++) {
          float e = fmaxf(z[r], z[r] * 0.01f);
          if (diag) {
            int jCol = bj * 16 + quad * 4 + r;
            e = (iRow < jCol) ? e : 0.f;
          }
          accS[nt] += e;
          accQ[nt] = fmaf(e, e, accQ[nt]);
        }
      }
    }
  }
#pragma unroll
  for (int nt = 0; nt < 4; nt++) {
    accS[nt] += __shfl_xor(accS[nt], 16); accS[nt] += __shfl_xor(accS[nt], 32);
    accQ[nt] += __shfl_xor(accQ[nt], 16); accQ[nt] += __shfl_xor(accQ[nt], 32);
  }
  if (quad == 0) {
#pragma unroll
    for (int nt = 0; nt < 4; nt++) {
      atomicAdd(&ssum[nt * 16 + l15], accS[nt]);
      atomicAdd(&ssq[nt * 16 + l15], accQ[nt]);
    }
  }
  __syncthreads();
  if (tid < 64) {
    int rep = blockIdx.x & 63;
    atomicAdd(&stats5[rep * 128 + tid], (double)ssum[tid]);
    atomicAdd(&stats5[rep * 128 + 64 + tid], (double)ssq[tid]);
  }
}

// Fold stats + BN + W6 into the DELTA-logit weights: prep[c] = sc_c*(w6b-w6a),
// prep[64] = (b6[1]-b6[0]) + sum_c sh_c*(w6b-w6a).
__global__ void k_prep5(const double* __restrict__ stats5, const float* __restrict__ g,
                        const float* __restrict__ bb, const float* __restrict__ W6,
                        const float* __restrict__ b6, float* __restrict__ prep,
                        double ecnt) {
  __shared__ float sdel[64];
  int c = threadIdx.x;
  if (c < 64) {
    double s1 = 0.0, s2 = 0.0;
    for (int r = 0; r < 64; r++) {
      s1 += stats5[r * 128 + c];
      s2 += stats5[r * 128 + 64 + c];
    }
    double mean = s1 / ecnt;
    double var = s2 / ecnt - mean * mean;
    if (var < 0.0) var = 0.0;
    float a = (float)((double)g[c] / sqrt(var + 1e-5));
    float sh = (float)((double)bb[c] - mean * (double)a);
    float dw = W6[2 * c + 1] - W6[2 * c];
    prep[c] = a * dw;
    sdel[c] = sh * dw;
  }
  __syncthreads();
  if (c == 0) {
    float t = b6[1] - b6[0];
    for (int k = 0; k < 64; k++) t += sdel[k];
    prep[64] = t;
  }
}

// ---------------------------------------------------------------------------
// Edge pass 2 (MFMA, swapped operands): W5 = A (channels = M), m = B (pairs = N).
// Each lane's C column holds ALL channels for one pair -> channel contraction
// is an in-register fma chain + 2-shuffle quad butterfly. Delta-logit only.
// One 16x16 pair tile per block (8256 blocks).
// ---------------------------------------------------------------------------
__global__ __launch_bounds__(256) void k_edge2m(
    const float* __restrict__ H3, const short* __restrict__ W5Th,
    const short* __restrict__ W5Tl, const float* __restrict__ b5,
    const float* __restrict__ prep, float* __restrict__ outp) {
  __shared__ float sI[16][36];
  __shared__ float sJ[16][36];
  int tid = threadIdx.x;
  int w = tid >> 6, lane = tid & 63;
  int quad = lane >> 4, l15 = lane & 15;
  int q8 = quad * 8;
  int bi, bj;
  tile_decode(blockIdx.x, bi, bj);
  {
    int row = tid >> 3, c4 = (tid & 7) * 4;
    int grow = (row < 16) ? (bi * 16 + row) : (bj * 16 + row - 16);
    float4 v = *(const float4*)(H3 + (size_t)grow * 32 + c4);
    float* dst = (row < 16) ? &sI[row][c4] : &sJ[row - 16][c4];
    *(float4*)dst = v;
  }
  // A-operand: W5 split frags (channel row = Mt*16 + l15, k = q8+e) and
  // per-lane channel vectors (channel = Mt*16 + quad*4 + r).
  short8 ah[4], al[4];
  f32x4 b5v[4], uv[4];
#pragma unroll
  for (int Mt = 0; Mt < 4; Mt++) {
    ah[Mt] = *(const short8*)(W5Th + (Mt * 16 + l15) * 32 + q8);
    al[Mt] = *(const short8*)(W5Tl + (Mt * 16 + l15) * 32 + q8);
    b5v[Mt] = *(const f32x4*)(b5 + Mt * 16 + quad * 4);
    uv[Mt] = *(const f32x4*)(prep + Mt * 16 + quad * 4);
  }
  float dbase = prep[64];
  __syncthreads();

  const float* pJ = &sJ[l15][q8];
  float4 j0 = *(const float4*)pJ, j1 = *(const float4*)(pJ + 4);
  float dkeep = 0.f;
#pragma unroll
  for (int nt = 0; nt < 4; nt++) {
    const float* pI = &sI[4 * w + nt][q8];
    float4 i0 = *(const float4*)pI, i1 = *(const float4*)(pI + 4);
    float m[8] = {i0.x * j0.x, i0.y * j0.y, i0.z * j0.z, i0.w * j0.w,
                  i1.x * j1.x, i1.y * j1.y, i1.z * j1.z, i1.w * j1.w};
    short8 bh, bl;
    split_pack(m, bh, bl);
    float d = 0.f;
#pragma unroll
    for (int Mt = 0; Mt < 4; Mt++) {
      f32x4 z = b5v[Mt];
      z = __builtin_amdgcn_mfma_f32_16x16x32_bf16(al[Mt], bh, z, 0, 0, 0);
      z = __builtin_amdgcn_mfma_f32_16x16x32_bf16(ah[Mt], bl, z, 0, 0, 0);
      z = __builtin_amdgcn_mfma_f32_16x16x32_bf16(ah[Mt], bh, z, 0, 0, 0);
#pragma unroll
      for (int r = 0; r < 4; r++) {
        float e = fmaxf(z[r], z[r] * 0.01f);
        d = fmaf(e, uv[Mt][r], d);
      }
    }
    d += __shfl_xor(d, 16);
    d += __shfl_xor(d, 32);
    if (quad == nt) dkeep = d;
  }
  int i = bi * 16 + 4 * w + quad;
  int j = bj * 16 + l15;
  if (i < j) {
    float dd = dkeep + dbase;
    float ex = __expf(dd);
    float p0 = 1.f / (1.f + ex);
    float2 p = make_float2(p0, ex * p0);
    *(float2*)(outp + ((size_t)i * NN + j) * 2) = p;
    *(float2*)(outp + ((size_t)j * NN + i) * 2) = p;
  } else if (i == j) {
    *(float2*)(outp + ((size_t)i * NN + i) * 2) = make_float2(0.f, 0.f);
  }
}

// ---------------------------------------------------------------------------
extern "C" void kernel_launch(void* const* d_in, const int* in_sizes, int n_in,
                              void* d_out, int out_size, void* d_ws, size_t ws_size,
                              hipStream_t stream) {
  const float* nf   = (const float*)d_in[1];
  const float* eps1 = (const float*)d_in[2];
  const float* W1a  = (const float*)d_in[3];
  const float* b1a  = (const float*)d_in[4];
  const float* W1b  = (const float*)d_in[5];
  const float* b1b  = (const float*)d_in[6];
  const float* epsm = (const float*)d_in[7];
  const float* Wma  = (const float*)d_in[8];
  const float* bma  = (const float*)d_in[9];
  const float* Wmb  = (const float*)d_in[10];
  const float* bmb  = (const float*)d_in[11];
  const float* bnmg = (const float*)d_in[12];
  const float* bnmb = (const float*)d_in[13];
  const float* epsl = (const float*)d_in[14];
  const float* Wla  = (const float*)d_in[15];
  const float* bla  = (const float*)d_in[16];
  const float* Wlb  = (const float*)d_in[17];
  const float* blb  = (const float*)d_in[18];
  const float* W5   = (const float*)d_in[19];
  const float* b5   = (const float*)d_in[20];
  const float* bn5g = (const float*)d_in[21];
  const float* bn5b = (const float*)d_in[22];
  const float* W6   = (const float*)d_in[23];
  const float* b6   = (const float*)d_in[24];
  double ecnt = (double)in_sizes[25];
  float* out = (float*)d_out;

  float* w = (float*)d_ws;
  float* h1   = w;                         // 2048*64
  float* h2   = w + 131072;                // 2048*64
  float* h3   = w + 262144;                // 2048*32
  float* cs1  = w + 327680;                // 64*32
  float* cs2  = w + 329728;                // 64*64
  float* csr  = w + 333824;                // 64*64
  float* prep = w + 337920;                // 192
  short* w5hi = (short*)(w + 338112);      // 2048 shorts
  short* w5lo = (short*)(w + 339136);      // 2048 shorts
  double* statsM = (double*)(w + 340160);  // 2048 doubles (16-rep stats)
  double* stats5 = statsM + 2048;          // 64*128 doubles

  // node pipeline: 4 flat kernels
  k_init<<<64, 256, 0, stream>>>(nf, W5, cs1, w5hi, w5lo, statsM);
  k_mlp32<32, 64, false, false, false, true><<<64, 256, 0, stream>>>(
      nf, cs1, eps1, W1a, b1a, W1b, b1b, h1, nullptr, nullptr, nullptr,
      nullptr, nullptr, cs2);
  k_mlp32<64, 64, true, false, false, true><<<64, 256, 0, stream>>>(
      h1, cs2, epsm, Wma, bma, Wmb, bmb, h2, nullptr, statsM, nullptr,
      nullptr, nullptr, csr);
  k_mlp32<64, 32, false, true, true, false><<<64, 256, 0, stream>>>(
      h2, csr, epsl, Wla, bla, Wlb, blb, h3, nf, nullptr, statsM,
      bnmg, bnmb, nullptr);

  // edge predictor
  const int T = 8256;   // 128*129/2 16x16 tiles
  const int NB = 2064;  // edge1: 4 tiles per block (grid-strided)
  k_edge1m<<<NB, 256, 0, stream>>>(h3, w5hi, w5lo, b5, stats5, T, NB);
  k_prep5<<<1, 64, 0, stream>>>(stats5, bn5g, bn5b, W6, b6, prep, ecnt);
  k_edge2m<<<T, 256, 0, stream>>>(h3, w5hi, w5lo, b5, prep, out);
}